// Round 9
// baseline (372.994 us; speedup 1.0000x reference)
//
#include <hip/hip_runtime.h>

#define PP    32      // nodes per graph
#define FF    16      // input features
#define HH    4       // heads
#define CC    32      // head dim
#define DD    128     // hidden (H*C)
#define EDIM  5
#define EPG   992     // edges per graph = P*(P-1)
#define NB    512     // graphs
#define NN    (NB * PP)                 // 16384 nodes
// workspace slots (floats): 4 x 8 MiB
#define WS_SLOT 2097152
#define WS_NEED ((size_t)4 * WS_SLOT * 4)

// ---- DPP helpers (HW-validated R4) ------------------------------------------
template <int CTRL>
__device__ __forceinline__ float dpp_add(float v) {
    int t = __builtin_amdgcn_update_dpp(0, __builtin_bit_cast(int, v), CTRL, 0xF, 0xF, true);
    return v + __builtin_bit_cast(float, t);
}
template <int CTRL>
__device__ __forceinline__ float dpp_mov(float v) {
    int t = __builtin_amdgcn_update_dpp(0, __builtin_bit_cast(int, v), CTRL, 0xF, 0xF, true);
    return __builtin_bit_cast(float, t);
}
__device__ __forceinline__ float red64(float v) {
    v = dpp_add<0x111>(v); v = dpp_add<0x112>(v); v = dpp_add<0x114>(v);
    v = dpp_add<0x118>(v); v = dpp_add<0x142>(v); v = dpp_add<0x143>(v);
    return v;                            // lane 63 holds the 64-lane sum
}
__device__ __forceinline__ float redquad(float v) {
    v = dpp_add<0xB1>(v);                // quad_perm [1,0,3,2]
    v = dpp_add<0x4E>(v);                // quad_perm [2,3,0,1]
    return v;
}
__device__ __forceinline__ float maxquad(float v) {
    v = fmaxf(v, dpp_mov<0xB1>(v));
    v = fmaxf(v, dpp_mov<0x4E>(v));
    return v;
}

// =============================================================================
// Multi-kernel pipeline.  Each phase kernel picks its OWN parallelism; bodies
// are lifted verbatim from the validated monolith (identical FMA order).
// Buffers: B0 = xl (layer1 then layer2), B1 = xr, B2 = scores/alpha, B3 = h.
// =============================================================================

// ---- K1: layer-1 node transforms.  thread = (n, j).  2M threads. ------------
extern "C" __global__ void __launch_bounds__(256)
k_t1(const float* __restrict__ x,
     const float* __restrict__ W1l, const float* __restrict__ b1l,
     const float* __restrict__ W1r, const float* __restrict__ b1r,
     float* __restrict__ xl, float* __restrict__ xr)
{
    const int idx = blockIdx.x * 256 + threadIdx.x;   // n*128 + j
    const int n = idx >> 7, j = idx & 127;
    float wl[16], wr[16], xv[16];
#pragma unroll
    for (int q = 0; q < 4; ++q) {
        *(float4*)(wl + q * 4) = *(const float4*)(W1l + j * FF + q * 4);
        *(float4*)(wr + q * 4) = *(const float4*)(W1r + j * FF + q * 4);
        *(float4*)(xv + q * 4) = *(const float4*)(x + n * FF + q * 4);
    }
    float al = b1l[j], ar = b1r[j];
#pragma unroll
    for (int k = 0; k < FF; ++k) {
        al = fmaf(wl[k], xv[k], al);
        ar = fmaf(wr[k], xv[k], ar);
    }
    xl[idx] = al;
    xr[idx] = ar;
}

// ---- K2: edge scores (both layers).  block = (graph, d-half); 512 thr. ------
// Lane map (monolith-proven): s = tid>>4, h = (tid>>2)&3, ch0 = (tid&15)*8.
// 1024 blocks x 8 waves = 32 waves/CU (8/SIMD) -> edge-attr latency TLP-hidden.
// Diagonal d==s computed on a clamped edge; softmax kernel discards it.
// sc layout: sc[((g*32+d)*4+h)*32 + s]  (contiguous s for softmax).
extern "C" __global__ void __launch_bounds__(512)
k_score(const float* __restrict__ xl, const float* __restrict__ xr,
        const float* __restrict__ eattr,
        const float* __restrict__ We, const float* __restrict__ att,
        float* __restrict__ sc)
{
    const int b = blockIdx.x;
    const int g = b >> 1, halfd = b & 1;
    const int tid = threadIdx.x;
    const int s   = tid >> 4;
    const int h   = (tid >> 2) & 3;
    const int ch0 = (tid & 15) * 8;
    const long eBase = (long)g * EPG;

    float we[40], at[8], xlv[8];
#pragma unroll
    for (int q = 0; q < 10; ++q)
        *(float4*)(we + q * 4) = *(const float4*)(We + ch0 * EDIM + q * 4);
    *(float4*)(at)      = *(const float4*)(att + ch0);
    *(float4*)(at + 4)  = *(const float4*)(att + ch0 + 4);
    *(float4*)(xlv)     = *(const float4*)(xl + (g * PP + s) * DD + ch0);
    *(float4*)(xlv + 4) = *(const float4*)(xl + (g * PP + s) * DD + ch0 + 4);

    const int d0 = halfd * 16;
    for (int dl = 0; dl < 16; ++dl) {
        const int d = d0 + dl;
        int jj = d - (d > s);
        if (jj > 30) jj = 30;                         // d==s==31 clamp (discarded)
        const float* ea = eattr + (eBase + s * 31 + jj) * EDIM;
        const float e0 = ea[0], e1 = ea[1], e2 = ea[2], e3 = ea[3], e4 = ea[4];
        float xrv[8];
        *(float4*)(xrv)     = *(const float4*)(xr + (g * PP + d) * DD + ch0);
        *(float4*)(xrv + 4) = *(const float4*)(xr + (g * PP + d) * DD + ch0 + 4);
        float acc0 = 0.f, acc1 = 0.f;
#pragma unroll
        for (int c = 0; c < 8; ++c) {
            float v = xlv[c] + xrv[c];
            const float* w = we + c * EDIM;
            v = fmaf(w[0], e0, v); v = fmaf(w[1], e1, v); v = fmaf(w[2], e2, v);
            v = fmaf(w[3], e3, v); v = fmaf(w[4], e4, v);
            v = fmaf(0.4f, fabsf(v), 0.6f * v);       // leaky_relu(., 0.2)
            if (c & 1) acc1 = fmaf(v, at[c], acc1);
            else       acc0 = fmaf(v, at[c], acc0);
        }
        const float r = redquad(acc0 + acc1);         // sum over 4 c4-chunks
        if ((tid & 3) == 0)
            sc[(((long)(g * PP + d) << 2) + h) * PP + s] = r;
    }
}

// ---- K3: segment softmax in place.  quad per column (g,d,h). ---------------
extern "C" __global__ void __launch_bounds__(256)
k_softmax(float* __restrict__ sc)
{
    const int idx = blockIdx.x * 256 + threadIdx.x;
    const int col = idx >> 2;                         // (g*32+d)*4+h
    const int r   = idx & 3;
    const int dd  = (col >> 2) & 31;                  // destination node d
    float* base = sc + (long)col * PP;
    float v[8];
    float mx = -3.4e38f;
#pragma unroll
    for (int i = 0; i < 8; ++i) {
        const int s = r * 8 + i;
        v[i] = base[s];
        mx = (s == dd) ? mx : fmaxf(mx, v[i]);
    }
    mx = maxquad(mx);
    float sum = 0.f;
#pragma unroll
    for (int i = 0; i < 8; ++i) {
        const int s = r * 8 + i;
        float ex = __expf(v[i] - mx);
        ex = (s == dd) ? 0.f : ex;                    // diagonal forced to 0
        v[i] = ex; sum += ex;
    }
    sum = redquad(sum);
    const float inv = 1.f / (sum + 1e-16f);
#pragma unroll
    for (int i = 0; i < 8; ++i)
        base[r * 8 + i] = v[i] * inv;
}

// ---- K4: aggregation.  thread = (n, ch4).  524K threads. -------------------
extern "C" __global__ void __launch_bounds__(256)
k_agg(const float* __restrict__ alpha, const float* __restrict__ msg,
      const float* __restrict__ bias, float* __restrict__ hout, const int relu)
{
    const int idx = blockIdx.x * 256 + threadIdx.x;   // n*32 + ch4
    const int n = idx >> 5, ch4 = idx & 31;
    const int g = n >> 5;
    const int h = ch4 >> 3;
    const float* ap = alpha + (((long)n << 2) + h) * PP;
    const float* bp = bias + ch4 * 4;
    float4 acc = make_float4(bp[0], bp[1], bp[2], bp[3]);
#pragma unroll
    for (int s = 0; s < PP; ++s) {
        const float a = ap[s];                        // alpha(d==s) == 0
        const float4 xv = *(const float4*)(msg + (g * PP + s) * DD + ch4 * 4);
        acc.x = fmaf(a, xv.x, acc.x);
        acc.y = fmaf(a, xv.y, acc.y);
        acc.z = fmaf(a, xv.z, acc.z);
        acc.w = fmaf(a, xv.w, acc.w);
    }
    if (relu) {
        acc.x = fmaxf(acc.x, 0.f); acc.y = fmaxf(acc.y, 0.f);
        acc.z = fmaxf(acc.z, 0.f); acc.w = fmaxf(acc.w, 0.f);
    }
    *(float4*)(hout + (long)n * DD + ch4 * 4) = acc;
}

// ---- K5: MeanSubtractionNorm + ReLU in place.  quad per (g, col). ----------
extern "C" __global__ void __launch_bounds__(256)
k_norm(float* __restrict__ h)
{
    const int idx = blockIdx.x * 256 + threadIdx.x;
    const int colg = idx >> 2;                        // g*128 + col
    const int r = idx & 3;
    const int g = colg >> 7, col = colg & 127;
    float v[8];
    float ssum = 0.f;
#pragma unroll
    for (int i = 0; i < 8; ++i) {
        v[i] = h[(long)(g * PP + r * 8 + i) * DD + col];
        ssum += v[i];
    }
    ssum = redquad(ssum);
    const float mn = ssum * (1.0f / 32.0f);
#pragma unroll
    for (int i = 0; i < 8; ++i)
        h[(long)(g * PP + r * 8 + i) * DD + col] = fmaxf(v[i] - mn, 0.f);
}

// ---- K6: layer-2 node transforms.  per-graph 512-thr block (monolith T2). --
extern "C" __global__ void __launch_bounds__(512)
k_t2(const float* __restrict__ h,
     const float* __restrict__ W2l, const float* __restrict__ b2l,
     const float* __restrict__ W2r, const float* __restrict__ b2r,
     float* __restrict__ xl, float* __restrict__ xr)
{
    const int g = blockIdx.x, tid = threadIdx.x;
    const int jj = tid & 63, d0 = (tid >> 6) * 4;
    const float* hb = h + (long)g * PP * DD;
    float accL0[4], accL1[4], accR0[4], accR1[4];
    const float bl0 = b2l[jj], bl1 = b2l[jj + 64];
    const float br0 = b2r[jj], br1 = b2r[jj + 64];
#pragma unroll
    for (int i = 0; i < 4; ++i) { accL0[i] = bl0; accL1[i] = bl1; accR0[i] = br0; accR1[i] = br1; }
    const float* WL0 = W2l + jj * DD;
    const float* WL1 = W2l + (jj + 64) * DD;
    const float* WR0 = W2r + jj * DD;
    const float* WR1 = W2r + (jj + 64) * DD;
    for (int k8 = 0; k8 < 16; ++k8) {
        const float4 l00 = *(const float4*)(WL0 + k8 * 8), l01 = *(const float4*)(WL0 + k8 * 8 + 4);
        const float4 l10 = *(const float4*)(WL1 + k8 * 8), l11 = *(const float4*)(WL1 + k8 * 8 + 4);
        const float4 r00 = *(const float4*)(WR0 + k8 * 8), r01 = *(const float4*)(WR0 + k8 * 8 + 4);
        const float4 r10 = *(const float4*)(WR1 + k8 * 8), r11 = *(const float4*)(WR1 + k8 * 8 + 4);
#pragma unroll
        for (int i = 0; i < 4; ++i) {
            const float4 a0 = *(const float4*)(hb + (d0 + i) * DD + k8 * 8);
            const float4 a1 = *(const float4*)(hb + (d0 + i) * DD + k8 * 8 + 4);
            accL0[i] = fmaf(l00.x, a0.x, accL0[i]); accL0[i] = fmaf(l00.y, a0.y, accL0[i]);
            accL0[i] = fmaf(l00.z, a0.z, accL0[i]); accL0[i] = fmaf(l00.w, a0.w, accL0[i]);
            accL0[i] = fmaf(l01.x, a1.x, accL0[i]); accL0[i] = fmaf(l01.y, a1.y, accL0[i]);
            accL0[i] = fmaf(l01.z, a1.z, accL0[i]); accL0[i] = fmaf(l01.w, a1.w, accL0[i]);
            accL1[i] = fmaf(l10.x, a0.x, accL1[i]); accL1[i] = fmaf(l10.y, a0.y, accL1[i]);
            accL1[i] = fmaf(l10.z, a0.z, accL1[i]); accL1[i] = fmaf(l10.w, a0.w, accL1[i]);
            accL1[i] = fmaf(l11.x, a1.x, accL1[i]); accL1[i] = fmaf(l11.y, a1.y, accL1[i]);
            accL1[i] = fmaf(l11.z, a1.z, accL1[i]); accL1[i] = fmaf(l11.w, a1.w, accL1[i]);
            accR0[i] = fmaf(r00.x, a0.x, accR0[i]); accR0[i] = fmaf(r00.y, a0.y, accR0[i]);
            accR0[i] = fmaf(r00.z, a0.z, accR0[i]); accR0[i] = fmaf(r00.w, a0.w, accR0[i]);
            accR0[i] = fmaf(r01.x, a1.x, accR0[i]); accR0[i] = fmaf(r01.y, a1.y, accR0[i]);
            accR0[i] = fmaf(r01.z, a1.z, accR0[i]); accR0[i] = fmaf(r01.w, a1.w, accR0[i]);
            accR1[i] = fmaf(r10.x, a0.x, accR1[i]); accR1[i] = fmaf(r10.y, a0.y, accR1[i]);
            accR1[i] = fmaf(r10.z, a0.z, accR1[i]); accR1[i] = fmaf(r10.w, a0.w, accR1[i]);
            accR1[i] = fmaf(r11.x, a1.x, accR1[i]); accR1[i] = fmaf(r11.y, a1.y, accR1[i]);
            accR1[i] = fmaf(r11.z, a1.z, accR1[i]); accR1[i] = fmaf(r11.w, a1.w, accR1[i]);
        }
    }
#pragma unroll
    for (int i = 0; i < 4; ++i) {
        xl[(long)(g * PP + d0 + i) * DD + jj]      = accL0[i];
        xl[(long)(g * PP + d0 + i) * DD + jj + 64] = accL1[i];
        xr[(long)(g * PP + d0 + i) * DD + jj]      = accR0[i];
        xr[(long)(g * PP + d0 + i) * DD + jj + 64] = accR1[i];
    }
}

// ---- K10: pool + heads.  per-graph 512-thr block (monolith code). ----------
extern "C" __global__ void __launch_bounds__(512)
k_heads(const float* __restrict__ h2,
        const float* __restrict__ Wc1, const float* __restrict__ bc1,
        const float* __restrict__ Wc2, const float* __restrict__ bc2,
        const float* __restrict__ Ws1, const float* __restrict__ bs1,
        const float* __restrict__ Ws2, const float* __restrict__ bs2,
        const float* __restrict__ Wn1, const float* __restrict__ bn1,
        const float* __restrict__ Wn2, const float* __restrict__ bn2,
        float* __restrict__ out)
{
    __shared__ __align__(16) float sU[DD];
    const int g = blockIdx.x, tid = threadIdx.x;
    const float* hb = h2 + (long)g * PP * DD;

    // ---- global mean pool -> sU[0..127] (quad per column, monolith code)
    {
        const int col = tid >> 2, r = tid & 3;
        float ssum = 0.f;
#pragma unroll
        for (int i = 0; i < 8; ++i) ssum += hb[(r * 8 + i) * DD + col];
        ssum = redquad(ssum);
        if (r == 0) sU[col] = ssum * (1.0f / 32.0f);
    }
    __syncthreads();

    // ---- source-actor: fused Ws1-GEMM + Ws2 dot (monolith code, hb global)
    {
        const int jj = tid & 63, d0 = (tid >> 6) * 4;
        const float b0 = bs1[jj], b1 = bs1[jj + 64];
        float acc0[4], acc1[4];
#pragma unroll
        for (int i = 0; i < 4; ++i) { acc0[i] = b0; acc1[i] = b1; }
        const float* W0 = Ws1 + jj * DD;
        const float* W1 = Ws1 + (jj + 64) * DD;
        for (int k8 = 0; k8 < 16; ++k8) {
            const float4 w00 = *(const float4*)(W0 + k8 * 8), w01 = *(const float4*)(W0 + k8 * 8 + 4);
            const float4 w10 = *(const float4*)(W1 + k8 * 8), w11 = *(const float4*)(W1 + k8 * 8 + 4);
#pragma unroll
            for (int i = 0; i < 4; ++i) {
                const float4 a0 = *(const float4*)(hb + (d0 + i) * DD + k8 * 8);
                const float4 a1 = *(const float4*)(hb + (d0 + i) * DD + k8 * 8 + 4);
                acc0[i] = fmaf(w00.x, a0.x, acc0[i]); acc0[i] = fmaf(w00.y, a0.y, acc0[i]);
                acc0[i] = fmaf(w00.z, a0.z, acc0[i]); acc0[i] = fmaf(w00.w, a0.w, acc0[i]);
                acc0[i] = fmaf(w01.x, a1.x, acc0[i]); acc0[i] = fmaf(w01.y, a1.y, acc0[i]);
                acc0[i] = fmaf(w01.z, a1.z, acc0[i]); acc0[i] = fmaf(w01.w, a1.w, acc0[i]);
                acc1[i] = fmaf(w10.x, a0.x, acc1[i]); acc1[i] = fmaf(w10.y, a0.y, acc1[i]);
                acc1[i] = fmaf(w10.z, a0.z, acc1[i]); acc1[i] = fmaf(w10.w, a0.w, acc1[i]);
                acc1[i] = fmaf(w11.x, a1.x, acc1[i]); acc1[i] = fmaf(w11.y, a1.y, acc1[i]);
                acc1[i] = fmaf(w11.z, a1.z, acc1[i]); acc1[i] = fmaf(w11.w, a1.w, acc1[i]);
            }
        }
        const float ws2a = Ws2[jj], ws2b = Ws2[jj + 64];
        const float bias2s = bs2[0];
#pragma unroll
        for (int i = 0; i < 4; ++i) {
            const float t = fmaf(fmaxf(acc0[i], 0.f), ws2a, fmaxf(acc1[i], 0.f) * ws2b);
            const float r = red64(t);                 // lane 63 holds node logit
            if ((tid & 63) == 63) out[g * 34 + 2 + d0 + i] = r + bias2s;
        }
    }

    // ---- value / noop: wave 0 = critic, wave 1 = noop (monolith code)
    if (tid < 128) {
        const int w = tid >> 6, j = tid & 63;
        const float* Wa = (w ? Wn1 : Wc1);
        const float* ba = (w ? bn1 : bc1);
        const float* Wb = (w ? Wn2 : Wc2);
        const float  bb = (w ? bn2 : bc2)[0];
        float h0 = ba[j], h1 = ba[j + 64];
        const float* R0 = Wa + j * DD;
        const float* R1 = Wa + (j + 64) * DD;
#pragma unroll
        for (int k8 = 0; k8 < 16; ++k8) {
            const float4 g0 = *(const float4*)(sU + k8 * 8);
            const float4 g1 = *(const float4*)(sU + k8 * 8 + 4);
            const float4 p00 = *(const float4*)(R0 + k8 * 8), p01 = *(const float4*)(R0 + k8 * 8 + 4);
            const float4 p10 = *(const float4*)(R1 + k8 * 8), p11 = *(const float4*)(R1 + k8 * 8 + 4);
            h0 = fmaf(p00.x, g0.x, h0); h0 = fmaf(p00.y, g0.y, h0);
            h0 = fmaf(p00.z, g0.z, h0); h0 = fmaf(p00.w, g0.w, h0);
            h0 = fmaf(p01.x, g1.x, h0); h0 = fmaf(p01.y, g1.y, h0);
            h0 = fmaf(p01.z, g1.z, h0); h0 = fmaf(p01.w, g1.w, h0);
            h1 = fmaf(p10.x, g0.x, h1); h1 = fmaf(p10.y, g0.y, h1);
            h1 = fmaf(p10.z, g0.z, h1); h1 = fmaf(p10.w, g0.w, h1);
            h1 = fmaf(p11.x, g1.x, h1); h1 = fmaf(p11.y, g1.y, h1);
            h1 = fmaf(p11.z, g1.z, h1); h1 = fmaf(p11.w, g1.w, h1);
        }
        const float t = fmaf(fmaxf(h0, 0.f), Wb[j], fmaxf(h1, 0.f) * Wb[j + 64]);
        const float r = red64(t);
        if (j == 63) out[g * 34 + w] = r + bb;
    }
}

// =============================================================================
// Fallback monolith (R8 source, proven 142.6 us, absmax 3.7e-9) — used only if
// ws_size < 32 MiB.
// =============================================================================
__device__ __forceinline__ void mono_attention(const float* __restrict__ eattr,
                                          const float* __restrict__ We, const float* __restrict__ att,
                                          const float* __restrict__ bias,
                                          const float* __restrict__ sMsg, const float* __restrict__ sDst,
                                          float* __restrict__ sS, float* __restrict__ sOut,
                                          int tid, long eBase, bool relu)
{
    float* __restrict__ sE = sOut;
    {
        const int s  = tid >> 4;
        const int ch0 = (tid & 15) * 8;
        float we[40], at[8], xl[8];
#pragma unroll
        for (int q = 0; q < 10; ++q)
            *(float4*)(we + q * 4) = *(const float4*)(We + ch0 * EDIM + q * 4);
        *(float4*)(at)     = *(const float4*)(att + ch0);
        *(float4*)(at + 4) = *(const float4*)(att + ch0 + 4);
        *(float4*)(xl)     = *(const float4*)(sMsg + s * DD + ch0);
        *(float4*)(xl + 4) = *(const float4*)(sMsg + s * DD + ch0 + 4);
        for (int halfd = 0; halfd < 2; ++halfd) {
            const int d0 = halfd * 16;
            {
                const int dl = tid & 15;
                const int d = d0 + dl;
                int jj = d - (d > s);
                if (jj > 30) jj = 30;
                const float* ea = eattr + (eBase + s * 31 + jj) * EDIM;
                const float e0 = ea[0], e1 = ea[1], e2 = ea[2], e3 = ea[3], e4 = ea[4];
                float* p = sE + (((s << 4) | dl) << 3);
                *(float4*)p = make_float4(e0, e1, e2, e3);
                p[4] = e4;
            }
            __syncthreads();
            for (int dl = 0; dl < 16; ++dl) {
                const int d = d0 + dl;
                const float* ep = sE + (((s << 4) | dl) << 3);
                const float4 ef = *(const float4*)ep;
                const float e4v = ep[4];
                float xr[8];
                *(float4*)(xr)     = *(const float4*)(sDst + d * DD + ch0);
                *(float4*)(xr + 4) = *(const float4*)(sDst + d * DD + ch0 + 4);
                float acc0 = 0.f, acc1 = 0.f;
#pragma unroll
                for (int c = 0; c < 8; ++c) {
                    float v = xl[c] + xr[c];
                    const float* w = we + c * EDIM;
                    v = fmaf(w[0], ef.x, v); v = fmaf(w[1], ef.y, v); v = fmaf(w[2], ef.z, v);
                    v = fmaf(w[3], ef.w, v); v = fmaf(w[4], e4v, v);
                    v = fmaf(0.4f, fabsf(v), 0.6f * v);
                    if (c & 1) acc1 = fmaf(v, at[c], acc1);
                    else       acc0 = fmaf(v, at[c], acc0);
                }
                const float r = redquad(acc0 + acc1);
                if ((tid & 3) == 0)
                    sS[s * DD + d * HH + ((tid >> 2) & 3)] = r;
            }
            __syncthreads();
        }
    }
    {
        const int col = tid >> 2;
        const int r   = tid & 3;
        const int dd  = col >> 2;
        float v[8];
        float mx = -3.4e38f;
#pragma unroll
        for (int i = 0; i < 8; ++i) {
            const int s = r * 8 + i;
            v[i] = sS[s * DD + col];
            mx = (s == dd) ? mx : fmaxf(mx, v[i]);
        }
        mx = maxquad(mx);
        float sum = 0.f;
#pragma unroll
        for (int i = 0; i < 8; ++i) {
            const int s = r * 8 + i;
            float ex = __expf(v[i] - mx);
            ex = (s == dd) ? 0.f : ex;
            v[i] = ex; sum += ex;
        }
        sum = redquad(sum);
        const float inv = 1.f / (sum + 1e-16f);
#pragma unroll
        for (int i = 0; i < 8; ++i)
            sS[(r * 8 + i) * DD + col] = v[i] * inv;
    }
    __syncthreads();
    {
        const int d = tid >> 4, sub = tid & 15;
#pragma unroll
        for (int half = 0; half < 2; ++half) {
            const int ch4 = half * 16 + sub;
            const int idx = d * HH + (ch4 >> 3);
            const float* bp = bias + ch4 * 4;
            float4 acc = make_float4(bp[0], bp[1], bp[2], bp[3]);
#pragma unroll
            for (int s = 0; s < PP; ++s) {
                const float a = sS[s * DD + idx];
                const float4 xv = *(const float4*)(sMsg + s * DD + ch4 * 4);
                acc.x = fmaf(a, xv.x, acc.x);
                acc.y = fmaf(a, xv.y, acc.y);
                acc.z = fmaf(a, xv.z, acc.z);
                acc.w = fmaf(a, xv.w, acc.w);
            }
            if (relu) {
                acc.x = fmaxf(acc.x, 0.f); acc.y = fmaxf(acc.y, 0.f);
                acc.z = fmaxf(acc.z, 0.f); acc.w = fmaxf(acc.w, 0.f);
            }
            *(float4*)(sOut + d * DD + ch4 * 4) = acc;
        }
    }
}

extern "C" __global__ void __launch_bounds__(512)
planetwars_gnn_mono(const float* __restrict__ x, const float* __restrict__ eattr,
                    const float* __restrict__ W1l, const float* __restrict__ b1l,
                    const float* __restrict__ W1r, const float* __restrict__ b1r,
                    const float* __restrict__ W1e, const float* __restrict__ att1, const float* __restrict__ bias1,
                    const float* __restrict__ W2l, const float* __restrict__ b2l,
                    const float* __restrict__ W2r, const float* __restrict__ b2r,
                    const float* __restrict__ W2e, const float* __restrict__ att2, const float* __restrict__ bias2,
                    const float* __restrict__ Wc1, const float* __restrict__ bc1,
                    const float* __restrict__ Wc2, const float* __restrict__ bc2,
                    const float* __restrict__ Ws1, const float* __restrict__ bs1,
                    const float* __restrict__ Ws2, const float* __restrict__ bs2,
                    const float* __restrict__ Wn1, const float* __restrict__ bn1,
                    const float* __restrict__ Wn2, const float* __restrict__ bn2,
                    float* __restrict__ out)
{
    __shared__ __align__(16) float sA[PP * DD];
    __shared__ __align__(16) float sB[PP * DD];
    __shared__ __align__(16) float sH[PP * DD];
    __shared__ __align__(16) float sU[PP * DD];
    const int tid = threadIdx.x;
    const int g = blockIdx.x;
    const long eBase = (long)g * EPG;
    sU[tid] = x[g * PP * FF + tid];
    __syncthreads();
    {
        const int j = tid & 127, d0 = (tid >> 7) * 8;
        float wl[16], wr[16];
#pragma unroll
        for (int q = 0; q < 4; ++q) {
            *(float4*)(wl + q * 4) = *(const float4*)(W1l + j * FF + q * 4);
            *(float4*)(wr + q * 4) = *(const float4*)(W1r + j * FF + q * 4);
        }
        const float bl = b1l[j], br = b1r[j];
#pragma unroll
        for (int i = 0; i < 8; ++i) {
            const float* xr = sU + (d0 + i) * FF;
            float al = bl, ar = br;
#pragma unroll
            for (int k = 0; k < FF; ++k) {
                const float xv = xr[k];
                al = fmaf(wl[k], xv, al);
                ar = fmaf(wr[k], xv, ar);
            }
            sA[(d0 + i) * DD + j] = al;
            sB[(d0 + i) * DD + j] = ar;
        }
    }
    __syncthreads();
    mono_attention(eattr, W1e, att1, bias1, sA, sB, sU, sH, tid, eBase, false);
    __syncthreads();
    {
        const int col = tid >> 2, r = tid & 3;
        float v[8];
        float ssum = 0.f;
#pragma unroll
        for (int i = 0; i < 8; ++i) {
            v[i] = sH[(r * 8 + i) * DD + col];
            ssum += v[i];
        }
        ssum = redquad(ssum);
        const float mn = ssum * (1.0f / 32.0f);
#pragma unroll
        for (int i = 0; i < 8; ++i)
            sH[(r * 8 + i) * DD + col] = fmaxf(v[i] - mn, 0.f);
    }
    __syncthreads();
    {
        const int jj = tid & 63, d0 = (tid >> 6) * 4;
        float accL0[4], accL1[4], accR0[4], accR1[4];
        const float bl0 = b2l[jj], bl1 = b2l[jj + 64];
        const float br0 = b2r[jj], br1 = b2r[jj + 64];
#pragma unroll
        for (int i = 0; i < 4; ++i) { accL0[i] = bl0; accL1[i] = bl1; accR0[i] = br0; accR1[i] = br1; }
        const float* WL0 = W2l + jj * DD;
        const float* WL1 = W2l + (jj + 64) * DD;
        const float* WR0 = W2r + jj * DD;
        const float* WR1 = W2r + (jj + 64) * DD;
        for (int k8 = 0; k8 < 16; ++k8) {
            const float4 l00 = *(const float4*)(WL0 + k8 * 8), l01 = *(const float4*)(WL0 + k8 * 8 + 4);
            const float4 l10 = *(const float4*)(WL1 + k8 * 8), l11 = *(const float4*)(WL1 + k8 * 8 + 4);
            const float4 r00 = *(const float4*)(WR0 + k8 * 8), r01 = *(const float4*)(WR0 + k8 * 8 + 4);
            const float4 r10 = *(const float4*)(WR1 + k8 * 8), r11 = *(const float4*)(WR1 + k8 * 8 + 4);
#pragma unroll
            for (int i = 0; i < 4; ++i) {
                const float4 a0 = *(const float4*)(sH + (d0 + i) * DD + k8 * 8);
                const float4 a1 = *(const float4*)(sH + (d0 + i) * DD + k8 * 8 + 4);
                accL0[i] = fmaf(l00.x, a0.x, accL0[i]); accL0[i] = fmaf(l00.y, a0.y, accL0[i]);
                accL0[i] = fmaf(l00.z, a0.z, accL0[i]); accL0[i] = fmaf(l00.w, a0.w, accL0[i]);
                accL0[i] = fmaf(l01.x, a1.x, accL0[i]); accL0[i] = fmaf(l01.y, a1.y, accL0[i]);
                accL0[i] = fmaf(l01.z, a1.z, accL0[i]); accL0[i] = fmaf(l01.w, a1.w, accL0[i]);
                accL1[i] = fmaf(l10.x, a0.x, accL1[i]); accL1[i] = fmaf(l10.y, a0.y, accL1[i]);
                accL1[i] = fmaf(l10.z, a0.z, accL1[i]); accL1[i] = fmaf(l10.w, a0.w, accL1[i]);
                accL1[i] = fmaf(l11.x, a1.x, accL1[i]); accL1[i] = fmaf(l11.y, a1.y, accL1[i]);
                accL1[i] = fmaf(l11.z, a1.z, accL1[i]); accL1[i] = fmaf(l11.w, a1.w, accL1[i]);
                accR0[i] = fmaf(r00.x, a0.x, accR0[i]); accR0[i] = fmaf(r00.y, a0.y, accR0[i]);
                accR0[i] = fmaf(r00.z, a0.z, accR0[i]); accR0[i] = fmaf(r00.w, a0.w, accR0[i]);
                accR0[i] = fmaf(r01.x, a1.x, accR0[i]); accR0[i] = fmaf(r01.y, a1.y, accR0[i]);
                accR0[i] = fmaf(r01.z, a1.z, accR0[i]); accR0[i] = fmaf(r01.w, a1.w, accR0[i]);
                accR1[i] = fmaf(r10.x, a0.x, accR1[i]); accR1[i] = fmaf(r10.y, a0.y, accR1[i]);
                accR1[i] = fmaf(r10.z, a0.z, accR1[i]); accR1[i] = fmaf(r10.w, a0.w, accR1[i]);
                accR1[i] = fmaf(r11.x, a1.x, accR1[i]); accR1[i] = fmaf(r11.y, a1.y, accR1[i]);
                accR1[i] = fmaf(r11.z, a1.z, accR1[i]); accR1[i] = fmaf(r11.w, a1.w, accR1[i]);
            }
        }
#pragma unroll
        for (int i = 0; i < 4; ++i) {
            sA[(d0 + i) * DD + jj]      = accL0[i];
            sA[(d0 + i) * DD + jj + 64] = accL1[i];
            sB[(d0 + i) * DD + jj]      = accR0[i];
            sB[(d0 + i) * DD + jj + 64] = accR1[i];
        }
    }
    __syncthreads();
    mono_attention(eattr, W2e, att2, bias2, sA, sB, sU, sH, tid, eBase, true);
    __syncthreads();
    {
        const int col = tid >> 2, r = tid & 3;
        float ssum = 0.f;
#pragma unroll
        for (int i = 0; i < 8; ++i) ssum += sH[(r * 8 + i) * DD + col];
        ssum = redquad(ssum);
        if (r == 0) sU[col] = ssum * (1.0f / 32.0f);
    }
    __syncthreads();
    {
        const int jj = tid & 63, d0 = (tid >> 6) * 4;
        const float b0 = bs1[jj], b1 = bs1[jj + 64];
        float acc0[4], acc1[4];
#pragma unroll
        for (int i = 0; i < 4; ++i) { acc0[i] = b0; acc1[i] = b1; }
        const float* W0 = Ws1 + jj * DD;
        const float* W1 = Ws1 + (jj + 64) * DD;
        for (int k8 = 0; k8 < 16; ++k8) {
            const float4 w00 = *(const float4*)(W0 + k8 * 8), w01 = *(const float4*)(W0 + k8 * 8 + 4);
            const float4 w10 = *(const float4*)(W1 + k8 * 8), w11 = *(const float4*)(W1 + k8 * 8 + 4);
#pragma unroll
            for (int i = 0; i < 4; ++i) {
                const float4 a0 = *(const float4*)(sH + (d0 + i) * DD + k8 * 8);
                const float4 a1 = *(const float4*)(sH + (d0 + i) * DD + k8 * 8 + 4);
                acc0[i] = fmaf(w00.x, a0.x, acc0[i]); acc0[i] = fmaf(w00.y, a0.y, acc0[i]);
                acc0[i] = fmaf(w00.z, a0.z, acc0[i]); acc0[i] = fmaf(w00.w, a0.w, acc0[i]);
                acc0[i] = fmaf(w01.x, a1.x, acc0[i]); acc0[i] = fmaf(w01.y, a1.y, acc0[i]);
                acc0[i] = fmaf(w01.z, a1.z, acc0[i]); acc0[i] = fmaf(w01.w, a1.w, acc0[i]);
                acc1[i] = fmaf(w10.x, a0.x, acc1[i]); acc1[i] = fmaf(w10.y, a0.y, acc1[i]);
                acc1[i] = fmaf(w10.z, a0.z, acc1[i]); acc1[i] = fmaf(w10.w, a0.w, acc1[i]);
                acc1[i] = fmaf(w11.x, a1.x, acc1[i]); acc1[i] = fmaf(w11.y, a1.y, acc1[i]);
                acc1[i] = fmaf(w11.z, a1.z, acc1[i]); acc1[i] = fmaf(w11.w, a1.w, acc1[i]);
            }
        }
        const float ws2a = Ws2[jj], ws2b = Ws2[jj + 64];
        const float bias2s = bs2[0];
#pragma unroll
        for (int i = 0; i < 4; ++i) {
            const float t = fmaf(fmaxf(acc0[i], 0.f), ws2a, fmaxf(acc1[i], 0.f) * ws2b);
            const float r = red64(t);
            if ((tid & 63) == 63) out[g * 34 + 2 + d0 + i] = r + bias2s;
        }
    }
    if (tid < 128) {
        const int w = tid >> 6, j = tid & 63;
        const float* Wa = (w ? Wn1 : Wc1);
        const float* ba = (w ? bn1 : bc1);
        const float* Wb = (w ? Wn2 : Wc2);
        const float  bb = (w ? bn2 : bc2)[0];
        float h0 = ba[j], h1 = ba[j + 64];
        const float* R0 = Wa + j * DD;
        const float* R1 = Wa + (j + 64) * DD;
#pragma unroll
        for (int k8 = 0; k8 < 16; ++k8) {
            const float4 g0 = *(const float4*)(sU + k8 * 8);
            const float4 g1 = *(const float4*)(sU + k8 * 8 + 4);
            const float4 p00 = *(const float4*)(R0 + k8 * 8), p01 = *(const float4*)(R0 + k8 * 8 + 4);
            const float4 p10 = *(const float4*)(R1 + k8 * 8), p11 = *(const float4*)(R1 + k8 * 8 + 4);
            h0 = fmaf(p00.x, g0.x, h0); h0 = fmaf(p00.y, g0.y, h0);
            h0 = fmaf(p00.z, g0.z, h0); h0 = fmaf(p00.w, g0.w, h0);
            h0 = fmaf(p01.x, g1.x, h0); h0 = fmaf(p01.y, g1.y, h0);
            h0 = fmaf(p01.z, g1.z, h0); h0 = fmaf(p01.w, g1.w, h0);
            h1 = fmaf(p10.x, g0.x, h1); h1 = fmaf(p10.y, g0.y, h1);
            h1 = fmaf(p10.z, g0.z, h1); h1 = fmaf(p10.w, g0.w, h1);
            h1 = fmaf(p11.x, g1.x, h1); h1 = fmaf(p11.y, g1.y, h1);
            h1 = fmaf(p11.z, g1.z, h1); h1 = fmaf(p11.w, g1.w, h1);
        }
        const float t = fmaf(fmaxf(h0, 0.f), Wb[j], fmaxf(h1, 0.f) * Wb[j + 64]);
        const float r = red64(t);
        if (j == 63) out[g * 34 + w] = r + bb;
    }
}

// =============================================================================
extern "C" void kernel_launch(void* const* d_in, const int* in_sizes, int n_in,
                              void* d_out, int out_size, void* d_ws, size_t ws_size,
                              hipStream_t stream)
{
    (void)in_sizes; (void)n_in; (void)out_size;
    const float* x     = (const float*)d_in[0];
    const float* eattr = (const float*)d_in[2];
    const float *W1l = (const float*)d_in[3],  *b1l = (const float*)d_in[4];
    const float *W1r = (const float*)d_in[5],  *b1r = (const float*)d_in[6];
    const float *W1e = (const float*)d_in[7],  *att1 = (const float*)d_in[8],  *bias1 = (const float*)d_in[9];
    const float *W2l = (const float*)d_in[10], *b2l = (const float*)d_in[11];
    const float *W2r = (const float*)d_in[12], *b2r = (const float*)d_in[13];
    const float *W2e = (const float*)d_in[14], *att2 = (const float*)d_in[15], *bias2 = (const float*)d_in[16];
    const float *Wc1 = (const float*)d_in[17], *bc1 = (const float*)d_in[18];
    const float *Wc2 = (const float*)d_in[19], *bc2 = (const float*)d_in[20];
    const float *Ws1 = (const float*)d_in[21], *bs1 = (const float*)d_in[22];
    const float *Ws2 = (const float*)d_in[23], *bs2 = (const float*)d_in[24];
    const float *Wn1 = (const float*)d_in[25], *bn1 = (const float*)d_in[26];
    const float *Wn2 = (const float*)d_in[27], *bn2 = (const float*)d_in[28];
    float* out = (float*)d_out;

    if (d_ws == nullptr || ws_size < WS_NEED) {
        // fallback: proven monolith (142.6 us)
        planetwars_gnn_mono<<<dim3(NB), dim3(512), 0, stream>>>(
            x, eattr, W1l, b1l, W1r, b1r, W1e, att1, bias1,
            W2l, b2l, W2r, b2r, W2e, att2, bias2,
            Wc1, bc1, Wc2, bc2, Ws1, bs1, Ws2, bs2, Wn1, bn1, Wn2, bn2, out);
        return;
    }

    float* B0 = (float*)d_ws;                 // xl1 -> xl2 (messages)
    float* B1 = B0 + WS_SLOT;                 // xr1 -> xr2
    float* B2 = B0 + 2 * (long)WS_SLOT;       // scores -> alpha (in place)
    float* B3 = B0 + 3 * (long)WS_SLOT;       // h1 -> h1n -> h2

    k_t1     <<<dim3(NN * DD / 256), dim3(256), 0, stream>>>(x, W1l, b1l, W1r, b1r, B0, B1);
    k_score  <<<dim3(NB * 2),        dim3(512), 0, stream>>>(B0, B1, eattr, W1e, att1, B2);
    k_softmax<<<dim3(1024),          dim3(256), 0, stream>>>(B2);
    k_agg    <<<dim3(2048),          dim3(256), 0, stream>>>(B2, B0, bias1, B3, 0);
    k_norm   <<<dim3(1024),          dim3(256), 0, stream>>>(B3);
    k_t2     <<<dim3(NB),            dim3(512), 0, stream>>>(B3, W2l, b2l, W2r, b2r, B0, B1);
    k_score  <<<dim3(NB * 2),        dim3(512), 0, stream>>>(B0, B1, eattr, W2e, att2, B2);
    k_softmax<<<dim3(1024),          dim3(256), 0, stream>>>(B2);
    k_agg    <<<dim3(2048),          dim3(256), 0, stream>>>(B2, B0, bias2, B3, 1);
    k_heads  <<<dim3(NB),            dim3(512), 0, stream>>>(B3, Wc1, bc1, Wc2, bc2,
                                                             Ws1, bs1, Ws2, bs2,
                                                             Wn1, bn1, Wn2, bn2, out);
}

// Round 10
// 332.231 us; speedup vs baseline: 1.1227x; 1.1227x over previous
//
#include <hip/hip_runtime.h>

#define PP    32      // nodes per graph
#define FF    16      // input features
#define HH    4       // heads
#define CC    32      // head dim
#define DD    128     // hidden (H*C)
#define EDIM  5
#define EPG   992     // edges per graph = P*(P-1)
#define NB    512     // graphs
#define NN    (NB * PP)                 // 16384 nodes
// workspace slots (floats): 3 x 8 MiB
#define WS_SLOT 2097152
#define WS_NEED ((size_t)3 * WS_SLOT * 4)

// ---- DPP helpers (HW-validated R4) ------------------------------------------
template <int CTRL>
__device__ __forceinline__ float dpp_add(float v) {
    int t = __builtin_amdgcn_update_dpp(0, __builtin_bit_cast(int, v), CTRL, 0xF, 0xF, true);
    return v + __builtin_bit_cast(float, t);
}
template <int CTRL>
__device__ __forceinline__ float dpp_mov(float v) {
    int t = __builtin_amdgcn_update_dpp(0, __builtin_bit_cast(int, v), CTRL, 0xF, 0xF, true);
    return __builtin_bit_cast(float, t);
}
__device__ __forceinline__ float red64(float v) {
    v = dpp_add<0x111>(v); v = dpp_add<0x112>(v); v = dpp_add<0x114>(v);
    v = dpp_add<0x118>(v); v = dpp_add<0x142>(v); v = dpp_add<0x143>(v);
    return v;                            // lane 63 holds the 64-lane sum
}
__device__ __forceinline__ float redquad(float v) {
    v = dpp_add<0xB1>(v);                // quad_perm [1,0,3,2]
    v = dpp_add<0x4E>(v);                // quad_perm [2,3,0,1]
    return v;
}
__device__ __forceinline__ float maxquad(float v) {
    v = fmaxf(v, dpp_mov<0xB1>(v));
    v = fmaxf(v, dpp_mov<0x4E>(v));
    return v;
}

// =============================================================================
// Pipeline kernels.  ALL launch bounds use min-waves=4 -> 128-reg budget ->
// allocator lands at the proven ~64 (R6 half-law).  GEMM bodies stage
// activations in LDS.  FMA order identical to the validated monolith.
// Buffers: B0 = xl, B1 = xr, B2 = h.
// =============================================================================

// ---- K1: layer-1 node transforms.  thread = (n, j). ------------------------
extern "C" __global__ void __launch_bounds__(256, 4)
k_t1(const float* __restrict__ x,
     const float* __restrict__ W1l, const float* __restrict__ b1l,
     const float* __restrict__ W1r, const float* __restrict__ b1r,
     float* __restrict__ xl, float* __restrict__ xr)
{
    const int idx = blockIdx.x * 256 + threadIdx.x;   // n*128 + j
    const int n = idx >> 7, j = idx & 127;
    float wl[16], wr[16], xv[16];
#pragma unroll
    for (int q = 0; q < 4; ++q) {
        *(float4*)(wl + q * 4) = *(const float4*)(W1l + j * FF + q * 4);
        *(float4*)(wr + q * 4) = *(const float4*)(W1r + j * FF + q * 4);
        *(float4*)(xv + q * 4) = *(const float4*)(x + n * FF + q * 4);
    }
    float al = b1l[j], ar = b1r[j];
#pragma unroll
    for (int k = 0; k < FF; ++k) {
        al = fmaf(wl[k], xv[k], al);
        ar = fmaf(wr[k], xv[k], ar);
    }
    xl[idx] = al;
    xr[idx] = ar;
}

// ---- K2: fused attention (score + softmax + agg) per (graph, d-half). ------
// 1024 blocks x 512 thr, 8 KB LDS, ~64 VGPR -> 4 blocks/CU = 32 waves/CU.
// Score lane map (monolith-proven): s = tid>>4, h = (tid>>2)&3, ch0=(tid&15)*8.
// Scores live in LDS sS[s*64 + dl*4 + h]; aggregation reads msg from global xl.
// Diagonal d==s computed on a clamped edge, zeroed by the softmax.
extern "C" __global__ void __launch_bounds__(512, 4)
k_attn(const float* __restrict__ xl, const float* __restrict__ xr,
       const float* __restrict__ eattr,
       const float* __restrict__ We, const float* __restrict__ att,
       const float* __restrict__ bias,
       float* __restrict__ hout, const int relu)
{
    __shared__ __align__(16) float sS[PP * 64];       // 8 KB
    const int b = blockIdx.x;
    const int g = b >> 1, d0 = (b & 1) * 16;
    const int tid = threadIdx.x;
    const long eBase = (long)g * EPG;

    // ---- score phase
    {
        const int s   = tid >> 4;
        const int h4  = (tid >> 2) & 3;
        const int ch0 = (tid & 15) * 8;
        float we[40], at[8], xlv[8];
#pragma unroll
        for (int q = 0; q < 10; ++q)
            *(float4*)(we + q * 4) = *(const float4*)(We + ch0 * EDIM + q * 4);
        *(float4*)(at)      = *(const float4*)(att + ch0);
        *(float4*)(at + 4)  = *(const float4*)(att + ch0 + 4);
        *(float4*)(xlv)     = *(const float4*)(xl + (g * PP + s) * DD + ch0);
        *(float4*)(xlv + 4) = *(const float4*)(xl + (g * PP + s) * DD + ch0 + 4);

        for (int dl = 0; dl < 16; ++dl) {
            const int d = d0 + dl;
            int jj = d - (d > s);
            if (jj > 30) jj = 30;                     // d==s==31 clamp (discarded)
            const float* ea = eattr + (eBase + s * 31 + jj) * EDIM;
            const float e0 = ea[0], e1 = ea[1], e2 = ea[2], e3 = ea[3], e4 = ea[4];
            float xrv[8];
            *(float4*)(xrv)     = *(const float4*)(xr + (g * PP + d) * DD + ch0);
            *(float4*)(xrv + 4) = *(const float4*)(xr + (g * PP + d) * DD + ch0 + 4);
            float acc0 = 0.f, acc1 = 0.f;
#pragma unroll
            for (int c = 0; c < 8; ++c) {
                float v = xlv[c] + xrv[c];
                const float* w = we + c * EDIM;
                v = fmaf(w[0], e0, v); v = fmaf(w[1], e1, v); v = fmaf(w[2], e2, v);
                v = fmaf(w[3], e3, v); v = fmaf(w[4], e4, v);
                v = fmaf(0.4f, fabsf(v), 0.6f * v);   // leaky_relu(., 0.2)
                if (c & 1) acc1 = fmaf(v, at[c], acc1);
                else       acc0 = fmaf(v, at[c], acc0);
            }
            const float r = redquad(acc0 + acc1);     // sum over 4 c4-chunks
            if ((tid & 3) == 0)
                sS[s * 64 + dl * 4 + h4] = r;
        }
    }
    __syncthreads();
    // ---- segment softmax over s != d for the 64 columns (dl*4+h)
    if (tid < 256) {
        const int col = tid >> 2;                     // dl*4 + h
        const int r   = tid & 3;
        const int dd  = d0 + (col >> 2);              // destination node
        float v[8];
        float mx = -3.4e38f;
#pragma unroll
        for (int i = 0; i < 8; ++i) {
            const int s = r * 8 + i;
            v[i] = sS[s * 64 + col];
            mx = (s == dd) ? mx : fmaxf(mx, v[i]);
        }
        mx = maxquad(mx);
        float sum = 0.f;
#pragma unroll
        for (int i = 0; i < 8; ++i) {
            const int s = r * 8 + i;
            float ex = __expf(v[i] - mx);
            ex = (s == dd) ? 0.f : ex;                // diagonal forced to 0
            v[i] = ex; sum += ex;
        }
        sum = redquad(sum);
        const float inv = 1.f / (sum + 1e-16f);
#pragma unroll
        for (int i = 0; i < 8; ++i)
            sS[(r * 8 + i) * 64 + col] = v[i] * inv;
    }
    __syncthreads();
    // ---- aggregation for rows d0..d0+15: thread = (dl, float4-column)
    {
        const int dl = tid >> 5, ch4 = tid & 31;
        const int col = dl * 4 + (ch4 >> 3);
        const float* bp = bias + ch4 * 4;
        float4 acc = make_float4(bp[0], bp[1], bp[2], bp[3]);
#pragma unroll
        for (int s = 0; s < PP; ++s) {
            const float a = sS[s * 64 + col];         // alpha(d==s) == 0
            const float4 xv = *(const float4*)(xl + (g * PP + s) * DD + ch4 * 4);
            acc.x = fmaf(a, xv.x, acc.x);
            acc.y = fmaf(a, xv.y, acc.y);
            acc.z = fmaf(a, xv.z, acc.z);
            acc.w = fmaf(a, xv.w, acc.w);
        }
        if (relu) {
            acc.x = fmaxf(acc.x, 0.f); acc.y = fmaxf(acc.y, 0.f);
            acc.z = fmaxf(acc.z, 0.f); acc.w = fmaxf(acc.w, 0.f);
        }
        *(float4*)(hout + (long)(g * PP + d0 + dl) * DD + ch4 * 4) = acc;
    }
}

// ---- K3: MeanSubtractionNorm + ReLU in place.  quad per (g, col). ----------
extern "C" __global__ void __launch_bounds__(256, 4)
k_norm(float* __restrict__ h)
{
    const int idx = blockIdx.x * 256 + threadIdx.x;
    const int colg = idx >> 2;                        // g*128 + col
    const int r = idx & 3;
    const int g = colg >> 7, col = colg & 127;
    float v[8];
    float ssum = 0.f;
#pragma unroll
    for (int i = 0; i < 8; ++i) {
        v[i] = h[(long)(g * PP + r * 8 + i) * DD + col];
        ssum += v[i];
    }
    ssum = redquad(ssum);
    const float mn = ssum * (1.0f / 32.0f);
#pragma unroll
    for (int i = 0; i < 8; ++i)
        h[(long)(g * PP + r * 8 + i) * DD + col] = fmaxf(v[i] - mn, 0.f);
}

// ---- K4: layer-2 node transforms per (graph, j-half).  LDS-staged h. -------
// 1024 blocks x 512 thr, 16 KB LDS -> 4 blocks/CU.  Monolith FMA order.
extern "C" __global__ void __launch_bounds__(512, 4)
k_t2(const float* __restrict__ h,
     const float* __restrict__ W2l, const float* __restrict__ b2l,
     const float* __restrict__ W2r, const float* __restrict__ b2r,
     float* __restrict__ xl, float* __restrict__ xr)
{
    __shared__ __align__(16) float sH[PP * DD];       // 16 KB
    const int b = blockIdx.x;
    const int g = b >> 1, jh = (b & 1) * 64;
    const int tid = threadIdx.x;
    {
        const float* hb = h + (long)g * PP * DD;
        *(float4*)(sH + tid * 8)     = *(const float4*)(hb + tid * 8);
        *(float4*)(sH + tid * 8 + 4) = *(const float4*)(hb + tid * 8 + 4);
    }
    __syncthreads();
    const int j = jh + (tid & 63), d0 = (tid >> 6) * 4;
    float accL[4], accR[4];
    const float bl = b2l[j], br = b2r[j];
#pragma unroll
    for (int i = 0; i < 4; ++i) { accL[i] = bl; accR[i] = br; }
    const float* WL = W2l + j * DD;
    const float* WR = W2r + j * DD;
    for (int k8 = 0; k8 < 16; ++k8) {
        const float4 l0 = *(const float4*)(WL + k8 * 8), l1 = *(const float4*)(WL + k8 * 8 + 4);
        const float4 r0 = *(const float4*)(WR + k8 * 8), r1 = *(const float4*)(WR + k8 * 8 + 4);
#pragma unroll
        for (int i = 0; i < 4; ++i) {
            const float4 a0 = *(const float4*)(sH + (d0 + i) * DD + k8 * 8);
            const float4 a1 = *(const float4*)(sH + (d0 + i) * DD + k8 * 8 + 4);
            accL[i] = fmaf(l0.x, a0.x, accL[i]); accL[i] = fmaf(l0.y, a0.y, accL[i]);
            accL[i] = fmaf(l0.z, a0.z, accL[i]); accL[i] = fmaf(l0.w, a0.w, accL[i]);
            accL[i] = fmaf(l1.x, a1.x, accL[i]); accL[i] = fmaf(l1.y, a1.y, accL[i]);
            accL[i] = fmaf(l1.z, a1.z, accL[i]); accL[i] = fmaf(l1.w, a1.w, accL[i]);
            accR[i] = fmaf(r0.x, a0.x, accR[i]); accR[i] = fmaf(r0.y, a0.y, accR[i]);
            accR[i] = fmaf(r0.z, a0.z, accR[i]); accR[i] = fmaf(r0.w, a0.w, accR[i]);
            accR[i] = fmaf(r1.x, a1.x, accR[i]); accR[i] = fmaf(r1.y, a1.y, accR[i]);
            accR[i] = fmaf(r1.z, a1.z, accR[i]); accR[i] = fmaf(r1.w, a1.w, accR[i]);
        }
    }
#pragma unroll
    for (int i = 0; i < 4; ++i) {
        xl[(long)(g * PP + d0 + i) * DD + j] = accL[i];
        xr[(long)(g * PP + d0 + i) * DD + j] = accR[i];
    }
}

// ---- K5: pool + heads.  per-graph 512-thr block, LDS-staged h2. ------------
extern "C" __global__ void __launch_bounds__(512, 4)
k_heads(const float* __restrict__ h2,
        const float* __restrict__ Wc1, const float* __restrict__ bc1,
        const float* __restrict__ Wc2, const float* __restrict__ bc2,
        const float* __restrict__ Ws1, const float* __restrict__ bs1,
        const float* __restrict__ Ws2, const float* __restrict__ bs2,
        const float* __restrict__ Wn1, const float* __restrict__ bn1,
        const float* __restrict__ Wn2, const float* __restrict__ bn2,
        float* __restrict__ out)
{
    __shared__ __align__(16) float sH[PP * DD];       // 16 KB
    __shared__ __align__(16) float sU[DD];
    const int g = blockIdx.x, tid = threadIdx.x;
    {
        const float* hb = h2 + (long)g * PP * DD;
        *(float4*)(sH + tid * 8)     = *(const float4*)(hb + tid * 8);
        *(float4*)(sH + tid * 8 + 4) = *(const float4*)(hb + tid * 8 + 4);
    }
    __syncthreads();

    // ---- global mean pool -> sU[0..127] (quad per column)
    {
        const int col = tid >> 2, r = tid & 3;
        float ssum = 0.f;
#pragma unroll
        for (int i = 0; i < 8; ++i) ssum += sH[(r * 8 + i) * DD + col];
        ssum = redquad(ssum);
        if (r == 0) sU[col] = ssum * (1.0f / 32.0f);
    }
    __syncthreads();

    // ---- source-actor: fused Ws1-GEMM + Ws2 dot (monolith code)
    {
        const int jj = tid & 63, d0 = (tid >> 6) * 4;
        const float b0 = bs1[jj], b1 = bs1[jj + 64];
        float acc0[4], acc1[4];
#pragma unroll
        for (int i = 0; i < 4; ++i) { acc0[i] = b0; acc1[i] = b1; }
        const float* W0 = Ws1 + jj * DD;
        const float* W1 = Ws1 + (jj + 64) * DD;
        for (int k8 = 0; k8 < 16; ++k8) {
            const float4 w00 = *(const float4*)(W0 + k8 * 8), w01 = *(const float4*)(W0 + k8 * 8 + 4);
            const float4 w10 = *(const float4*)(W1 + k8 * 8), w11 = *(const float4*)(W1 + k8 * 8 + 4);
#pragma unroll
            for (int i = 0; i < 4; ++i) {
                const float4 a0 = *(const float4*)(sH + (d0 + i) * DD + k8 * 8);
                const float4 a1 = *(const float4*)(sH + (d0 + i) * DD + k8 * 8 + 4);
                acc0[i] = fmaf(w00.x, a0.x, acc0[i]); acc0[i] = fmaf(w00.y, a0.y, acc0[i]);
                acc0[i] = fmaf(w00.z, a0.z, acc0[i]); acc0[i] = fmaf(w00.w, a0.w, acc0[i]);
                acc0[i] = fmaf(w01.x, a1.x, acc0[i]); acc0[i] = fmaf(w01.y, a1.y, acc0[i]);
                acc0[i] = fmaf(w01.z, a1.z, acc0[i]); acc0[i] = fmaf(w01.w, a1.w, acc0[i]);
                acc1[i] = fmaf(w10.x, a0.x, acc1[i]); acc1[i] = fmaf(w10.y, a0.y, acc1[i]);
                acc1[i] = fmaf(w10.z, a0.z, acc1[i]); acc1[i] = fmaf(w10.w, a0.w, acc1[i]);
                acc1[i] = fmaf(w11.x, a1.x, acc1[i]); acc1[i] = fmaf(w11.y, a1.y, acc1[i]);
                acc1[i] = fmaf(w11.z, a1.z, acc1[i]); acc1[i] = fmaf(w11.w, a1.w, acc1[i]);
            }
        }
        const float ws2a = Ws2[jj], ws2b = Ws2[jj + 64];
        const float bias2s = bs2[0];
#pragma unroll
        for (int i = 0; i < 4; ++i) {
            const float t = fmaf(fmaxf(acc0[i], 0.f), ws2a, fmaxf(acc1[i], 0.f) * ws2b);
            const float r = red64(t);                 // lane 63 holds node logit
            if ((tid & 63) == 63) out[g * 34 + 2 + d0 + i] = r + bias2s;
        }
    }

    // ---- value / noop: wave 0 = critic, wave 1 = noop
    if (tid < 128) {
        const int w = tid >> 6, j = tid & 63;
        const float* Wa = (w ? Wn1 : Wc1);
        const float* ba = (w ? bn1 : bc1);
        const float* Wb = (w ? Wn2 : Wc2);
        const float  bb = (w ? bn2 : bc2)[0];
        float h0 = ba[j], h1 = ba[j + 64];
        const float* R0 = Wa + j * DD;
        const float* R1 = Wa + (j + 64) * DD;
#pragma unroll
        for (int k8 = 0; k8 < 16; ++k8) {
            const float4 g0 = *(const float4*)(sU + k8 * 8);
            const float4 g1 = *(const float4*)(sU + k8 * 8 + 4);
            const float4 p00 = *(const float4*)(R0 + k8 * 8), p01 = *(const float4*)(R0 + k8 * 8 + 4);
            const float4 p10 = *(const float4*)(R1 + k8 * 8), p11 = *(const float4*)(R1 + k8 * 8 + 4);
            h0 = fmaf(p00.x, g0.x, h0); h0 = fmaf(p00.y, g0.y, h0);
            h0 = fmaf(p00.z, g0.z, h0); h0 = fmaf(p00.w, g0.w, h0);
            h0 = fmaf(p01.x, g1.x, h0); h0 = fmaf(p01.y, g1.y, h0);
            h0 = fmaf(p01.z, g1.z, h0); h0 = fmaf(p01.w, g1.w, h0);
            h1 = fmaf(p10.x, g0.x, h1); h1 = fmaf(p10.y, g0.y, h1);
            h1 = fmaf(p10.z, g0.z, h1); h1 = fmaf(p10.w, g0.w, h1);
            h1 = fmaf(p11.x, g1.x, h1); h1 = fmaf(p11.y, g1.y, h1);
            h1 = fmaf(p11.z, g1.z, h1); h1 = fmaf(p11.w, g1.w, h1);
        }
        const float t = fmaf(fmaxf(h0, 0.f), Wb[j], fmaxf(h1, 0.f) * Wb[j + 64]);
        const float r = red64(t);
        if (j == 63) out[g * 34 + w] = r + bb;
    }
}

// =============================================================================
// Fallback monolith (R8 source, proven 142.6 us) — used only if ws too small.
// =============================================================================
__device__ __forceinline__ void mono_attention(const float* __restrict__ eattr,
                                          const float* __restrict__ We, const float* __restrict__ att,
                                          const float* __restrict__ bias,
                                          const float* __restrict__ sMsg, const float* __restrict__ sDst,
                                          float* __restrict__ sS, float* __restrict__ sOut,
                                          int tid, long eBase, bool relu)
{
    float* __restrict__ sE = sOut;
    {
        const int s  = tid >> 4;
        const int ch0 = (tid & 15) * 8;
        float we[40], at[8], xl[8];
#pragma unroll
        for (int q = 0; q < 10; ++q)
            *(float4*)(we + q * 4) = *(const float4*)(We + ch0 * EDIM + q * 4);
        *(float4*)(at)     = *(const float4*)(att + ch0);
        *(float4*)(at + 4) = *(const float4*)(att + ch0 + 4);
        *(float4*)(xl)     = *(const float4*)(sMsg + s * DD + ch0);
        *(float4*)(xl + 4) = *(const float4*)(sMsg + s * DD + ch0 + 4);
        for (int halfd = 0; halfd < 2; ++halfd) {
            const int d0 = halfd * 16;
            {
                const int dl = tid & 15;
                const int d = d0 + dl;
                int jj = d - (d > s);
                if (jj > 30) jj = 30;
                const float* ea = eattr + (eBase + s * 31 + jj) * EDIM;
                const float e0 = ea[0], e1 = ea[1], e2 = ea[2], e3 = ea[3], e4 = ea[4];
                float* p = sE + (((s << 4) | dl) << 3);
                *(float4*)p = make_float4(e0, e1, e2, e3);
                p[4] = e4;
            }
            __syncthreads();
            for (int dl = 0; dl < 16; ++dl) {
                const int d = d0 + dl;
                const float* ep = sE + (((s << 4) | dl) << 3);
                const float4 ef = *(const float4*)ep;
                const float e4v = ep[4];
                float xr[8];
                *(float4*)(xr)     = *(const float4*)(sDst + d * DD + ch0);
                *(float4*)(xr + 4) = *(const float4*)(sDst + d * DD + ch0 + 4);
                float acc0 = 0.f, acc1 = 0.f;
#pragma unroll
                for (int c = 0; c < 8; ++c) {
                    float v = xl[c] + xr[c];
                    const float* w = we + c * EDIM;
                    v = fmaf(w[0], ef.x, v); v = fmaf(w[1], ef.y, v); v = fmaf(w[2], ef.z, v);
                    v = fmaf(w[3], ef.w, v); v = fmaf(w[4], e4v, v);
                    v = fmaf(0.4f, fabsf(v), 0.6f * v);
                    if (c & 1) acc1 = fmaf(v, at[c], acc1);
                    else       acc0 = fmaf(v, at[c], acc0);
                }
                const float r = redquad(acc0 + acc1);
                if ((tid & 3) == 0)
                    sS[s * DD + d * HH + ((tid >> 2) & 3)] = r;
            }
            __syncthreads();
        }
    }
    {
        const int col = tid >> 2;
        const int r   = tid & 3;
        const int dd  = col >> 2;
        float v[8];
        float mx = -3.4e38f;
#pragma unroll
        for (int i = 0; i < 8; ++i) {
            const int s = r * 8 + i;
            v[i] = sS[s * DD + col];
            mx = (s == dd) ? mx : fmaxf(mx, v[i]);
        }
        mx = maxquad(mx);
        float sum = 0.f;
#pragma unroll
        for (int i = 0; i < 8; ++i) {
            const int s = r * 8 + i;
            float ex = __expf(v[i] - mx);
            ex = (s == dd) ? 0.f : ex;
            v[i] = ex; sum += ex;
        }
        sum = redquad(sum);
        const float inv = 1.f / (sum + 1e-16f);
#pragma unroll
        for (int i = 0; i < 8; ++i)
            sS[(r * 8 + i) * DD + col] = v[i] * inv;
    }
    __syncthreads();
    {
        const int d = tid >> 4, sub = tid & 15;
#pragma unroll
        for (int half = 0; half < 2; ++half) {
            const int ch4 = half * 16 + sub;
            const int idx = d * HH + (ch4 >> 3);
            const float* bp = bias + ch4 * 4;
            float4 acc = make_float4(bp[0], bp[1], bp[2], bp[3]);
#pragma unroll
            for (int s = 0; s < PP; ++s) {
                const float a = sS[s * DD + idx];
                const float4 xv = *(const float4*)(sMsg + s * DD + ch4 * 4);
                acc.x = fmaf(a, xv.x, acc.x);
                acc.y = fmaf(a, xv.y, acc.y);
                acc.z = fmaf(a, xv.z, acc.z);
                acc.w = fmaf(a, xv.w, acc.w);
            }
            if (relu) {
                acc.x = fmaxf(acc.x, 0.f); acc.y = fmaxf(acc.y, 0.f);
                acc.z = fmaxf(acc.z, 0.f); acc.w = fmaxf(acc.w, 0.f);
            }
            *(float4*)(sOut + d * DD + ch4 * 4) = acc;
        }
    }
}

extern "C" __global__ void __launch_bounds__(512)
planetwars_gnn_mono(const float* __restrict__ x, const float* __restrict__ eattr,
                    const float* __restrict__ W1l, const float* __restrict__ b1l,
                    const float* __restrict__ W1r, const float* __restrict__ b1r,
                    const float* __restrict__ W1e, const float* __restrict__ att1, const float* __restrict__ bias1,
                    const float* __restrict__ W2l, const float* __restrict__ b2l,
                    const float* __restrict__ W2r, const float* __restrict__ b2r,
                    const float* __restrict__ W2e, const float* __restrict__ att2, const float* __restrict__ bias2,
                    const float* __restrict__ Wc1, const float* __restrict__ bc1,
                    const float* __restrict__ Wc2, const float* __restrict__ bc2,
                    const float* __restrict__ Ws1, const float* __restrict__ bs1,
                    const float* __restrict__ Ws2, const float* __restrict__ bs2,
                    const float* __restrict__ Wn1, const float* __restrict__ bn1,
                    const float* __restrict__ Wn2, const float* __restrict__ bn2,
                    float* __restrict__ out)
{
    __shared__ __align__(16) float sA[PP * DD];
    __shared__ __align__(16) float sB[PP * DD];
    __shared__ __align__(16) float sH[PP * DD];
    __shared__ __align__(16) float sU[PP * DD];
    const int tid = threadIdx.x;
    const int g = blockIdx.x;
    const long eBase = (long)g * EPG;
    sU[tid] = x[g * PP * FF + tid];
    __syncthreads();
    {
        const int j = tid & 127, d0 = (tid >> 7) * 8;
        float wl[16], wr[16];
#pragma unroll
        for (int q = 0; q < 4; ++q) {
            *(float4*)(wl + q * 4) = *(const float4*)(W1l + j * FF + q * 4);
            *(float4*)(wr + q * 4) = *(const float4*)(W1r + j * FF + q * 4);
        }
        const float bl = b1l[j], br = b1r[j];
#pragma unroll
        for (int i = 0; i < 8; ++i) {
            const float* xr = sU + (d0 + i) * FF;
            float al = bl, ar = br;
#pragma unroll
            for (int k = 0; k < FF; ++k) {
                const float xv = xr[k];
                al = fmaf(wl[k], xv, al);
                ar = fmaf(wr[k], xv, ar);
            }
            sA[(d0 + i) * DD + j] = al;
            sB[(d0 + i) * DD + j] = ar;
        }
    }
    __syncthreads();
    mono_attention(eattr, W1e, att1, bias1, sA, sB, sU, sH, tid, eBase, false);
    __syncthreads();
    {
        const int col = tid >> 2, r = tid & 3;
        float v[8];
        float ssum = 0.f;
#pragma unroll
        for (int i = 0; i < 8; ++i) {
            v[i] = sH[(r * 8 + i) * DD + col];
            ssum += v[i];
        }
        ssum = redquad(ssum);
        const float mn = ssum * (1.0f / 32.0f);
#pragma unroll
        for (int i = 0; i < 8; ++i)
            sH[(r * 8 + i) * DD + col] = fmaxf(v[i] - mn, 0.f);
    }
    __syncthreads();
    {
        const int jj = tid & 63, d0 = (tid >> 6) * 4;
        float accL0[4], accL1[4], accR0[4], accR1[4];
        const float bl0 = b2l[jj], bl1 = b2l[jj + 64];
        const float br0 = b2r[jj], br1 = b2r[jj + 64];
#pragma unroll
        for (int i = 0; i < 4; ++i) { accL0[i] = bl0; accL1[i] = bl1; accR0[i] = br0; accR1[i] = br1; }
        const float* WL0 = W2l + jj * DD;
        const float* WL1 = W2l + (jj + 64) * DD;
        const float* WR0 = W2r + jj * DD;
        const float* WR1 = W2r + (jj + 64) * DD;
        for (int k8 = 0; k8 < 16; ++k8) {
            const float4 l00 = *(const float4*)(WL0 + k8 * 8), l01 = *(const float4*)(WL0 + k8 * 8 + 4);
            const float4 l10 = *(const float4*)(WL1 + k8 * 8), l11 = *(const float4*)(WL1 + k8 * 8 + 4);
            const float4 r00 = *(const float4*)(WR0 + k8 * 8), r01 = *(const float4*)(WR0 + k8 * 8 + 4);
            const float4 r10 = *(const float4*)(WR1 + k8 * 8), r11 = *(const float4*)(WR1 + k8 * 8 + 4);
#pragma unroll
            for (int i = 0; i < 4; ++i) {
                const float4 a0 = *(const float4*)(sH + (d0 + i) * DD + k8 * 8);
                const float4 a1 = *(const float4*)(sH + (d0 + i) * DD + k8 * 8 + 4);
                accL0[i] = fmaf(l00.x, a0.x, accL0[i]); accL0[i] = fmaf(l00.y, a0.y, accL0[i]);
                accL0[i] = fmaf(l00.z, a0.z, accL0[i]); accL0[i] = fmaf(l00.w, a0.w, accL0[i]);
                accL0[i] = fmaf(l01.x, a1.x, accL0[i]); accL0[i] = fmaf(l01.y, a1.y, accL0[i]);
                accL0[i] = fmaf(l01.z, a1.z, accL0[i]); accL0[i] = fmaf(l01.w, a1.w, accL0[i]);
                accL1[i] = fmaf(l10.x, a0.x, accL1[i]); accL1[i] = fmaf(l10.y, a0.y, accL1[i]);
                accL1[i] = fmaf(l10.z, a0.z, accL1[i]); accL1[i] = fmaf(l10.w, a0.w, accL1[i]);
                accL1[i] = fmaf(l11.x, a1.x, accL1[i]); accL1[i] = fmaf(l11.y, a1.y, accL1[i]);
                accL1[i] = fmaf(l11.z, a1.z, accL1[i]); accL1[i] = fmaf(l11.w, a1.w, accL1[i]);
                accR0[i] = fmaf(r00.x, a0.x, accR0[i]); accR0[i] = fmaf(r00.y, a0.y, accR0[i]);
                accR0[i] = fmaf(r00.z, a0.z, accR0[i]); accR0[i] = fmaf(r00.w, a0.w, accR0[i]);
                accR0[i] = fmaf(r01.x, a1.x, accR0[i]); accR0[i] = fmaf(r01.y, a1.y, accR0[i]);
                accR0[i] = fmaf(r01.z, a1.z, accR0[i]); accR0[i] = fmaf(r01.w, a1.w, accR0[i]);
                accR1[i] = fmaf(r10.x, a0.x, accR1[i]); accR1[i] = fmaf(r10.y, a0.y, accR1[i]);
                accR1[i] = fmaf(r10.z, a0.z, accR1[i]); accR1[i] = fmaf(r10.w, a0.w, accR1[i]);
                accR1[i] = fmaf(r11.x, a1.x, accR1[i]); accR1[i] = fmaf(r11.y, a1.y, accR1[i]);
                accR1[i] = fmaf(r11.z, a1.z, accR1[i]); accR1[i] = fmaf(r11.w, a1.w, accR1[i]);
            }
        }
#pragma unroll
        for (int i = 0; i < 4; ++i) {
            sA[(d0 + i) * DD + jj]      = accL0[i];
            sA[(d0 + i) * DD + jj + 64] = accL1[i];
            sB[(d0 + i) * DD + jj]      = accR0[i];
            sB[(d0 + i) * DD + jj + 64] = accR1[i];
        }
    }
    __syncthreads();
    mono_attention(eattr, W2e, att2, bias2, sA, sB, sU, sH, tid, eBase, true);
    __syncthreads();
    {
        const int col = tid >> 2, r = tid & 3;
        float ssum = 0.f;
#pragma unroll
        for (int i = 0; i < 8; ++i) ssum += sH[(r * 8 + i) * DD + col];
        ssum = redquad(ssum);
        if (r == 0) sU[col] = ssum * (1.0f / 32.0f);
    }
    __syncthreads();
    {
        const int jj = tid & 63, d0 = (tid >> 6) * 4;
        const float b0 = bs1[jj], b1 = bs1[jj + 64];
        float acc0[4], acc1[4];
#pragma unroll
        for (int i = 0; i < 4; ++i) { acc0[i] = b0; acc1[i] = b1; }
        const float* W0 = Ws1 + jj * DD;
        const float* W1 = Ws1 + (jj + 64) * DD;
        for (int k8 = 0; k8 < 16; ++k8) {
            const float4 w00 = *(const float4*)(W0 + k8 * 8), w01 = *(const float4*)(W0 + k8 * 8 + 4);
            const float4 w10 = *(const float4*)(W1 + k8 * 8), w11 = *(const float4*)(W1 + k8 * 8 + 4);
#pragma unroll
            for (int i = 0; i < 4; ++i) {
                const float4 a0 = *(const float4*)(sH + (d0 + i) * DD + k8 * 8);
                const float4 a1 = *(const float4*)(sH + (d0 + i) * DD + k8 * 8 + 4);
                acc0[i] = fmaf(w00.x, a0.x, acc0[i]); acc0[i] = fmaf(w00.y, a0.y, acc0[i]);
                acc0[i] = fmaf(w00.z, a0.z, acc0[i]); acc0[i] = fmaf(w00.w, a0.w, acc0[i]);
                acc0[i] = fmaf(w01.x, a1.x, acc0[i]); acc0[i] = fmaf(w01.y, a1.y, acc0[i]);
                acc0[i] = fmaf(w01.z, a1.z, acc0[i]); acc0[i] = fmaf(w01.w, a1.w, acc0[i]);
                acc1[i] = fmaf(w10.x, a0.x, acc1[i]); acc1[i] = fmaf(w10.y, a0.y, acc1[i]);
                acc1[i] = fmaf(w10.z, a0.z, acc1[i]); acc1[i] = fmaf(w10.w, a0.w, acc1[i]);
                acc1[i] = fmaf(w11.x, a1.x, acc1[i]); acc1[i] = fmaf(w11.y, a1.y, acc1[i]);
                acc1[i] = fmaf(w11.z, a1.z, acc1[i]); acc1[i] = fmaf(w11.w, a1.w, acc1[i]);
            }
        }
        const float ws2a = Ws2[jj], ws2b = Ws2[jj + 64];
        const float bias2s = bs2[0];
#pragma unroll
        for (int i = 0; i < 4; ++i) {
            const float t = fmaf(fmaxf(acc0[i], 0.f), ws2a, fmaxf(acc1[i], 0.f) * ws2b);
            const float r = red64(t);
            if ((tid & 63) == 63) out[g * 34 + 2 + d0 + i] = r + bias2s;
        }
    }
    if (tid < 128) {
        const int w = tid >> 6, j = tid & 63;
        const float* Wa = (w ? Wn1 : Wc1);
        const float* ba = (w ? bn1 : bc1);
        const float* Wb = (w ? Wn2 : Wc2);
        const float  bb = (w ? bn2 : bc2)[0];
        float h0 = ba[j], h1 = ba[j + 64];
        const float* R0 = Wa + j * DD;
        const float* R1 = Wa + (j + 64) * DD;
#pragma unroll
        for (int k8 = 0; k8 < 16; ++k8) {
            const float4 g0 = *(const float4*)(sU + k8 * 8);
            const float4 g1 = *(const float4*)(sU + k8 * 8 + 4);
            const float4 p00 = *(const float4*)(R0 + k8 * 8), p01 = *(const float4*)(R0 + k8 * 8 + 4);
            const float4 p10 = *(const float4*)(R1 + k8 * 8), p11 = *(const float4*)(R1 + k8 * 8 + 4);
            h0 = fmaf(p00.x, g0.x, h0); h0 = fmaf(p00.y, g0.y, h0);
            h0 = fmaf(p00.z, g0.z, h0); h0 = fmaf(p00.w, g0.w, h0);
            h0 = fmaf(p01.x, g1.x, h0); h0 = fmaf(p01.y, g1.y, h0);
            h0 = fmaf(p01.z, g1.z, h0); h0 = fmaf(p01.w, g1.w, h0);
            h1 = fmaf(p10.x, g0.x, h1); h1 = fmaf(p10.y, g0.y, h1);
            h1 = fmaf(p10.z, g0.z, h1); h1 = fmaf(p10.w, g0.w, h1);
            h1 = fmaf(p11.x, g1.x, h1); h1 = fmaf(p11.y, g1.y, h1);
            h1 = fmaf(p11.z, g1.z, h1); h1 = fmaf(p11.w, g1.w, h1);
        }
        const float t = fmaf(fmaxf(h0, 0.f), Wb[j], fmaxf(h1, 0.f) * Wb[j + 64]);
        const float r = red64(t);
        if (j == 63) out[g * 34 + w] = r + bb;
    }
}

// =============================================================================
extern "C" void kernel_launch(void* const* d_in, const int* in_sizes, int n_in,
                              void* d_out, int out_size, void* d_ws, size_t ws_size,
                              hipStream_t stream)
{
    (void)in_sizes; (void)n_in; (void)out_size;
    const float* x     = (const float*)d_in[0];
    const float* eattr = (const float*)d_in[2];
    const float *W1l = (const float*)d_in[3],  *b1l = (const float*)d_in[4];
    const float *W1r = (const float*)d_in[5],  *b1r = (const float*)d_in[6];
    const float *W1e = (const float*)d_in[7],  *att1 = (const float*)d_in[8],  *bias1 = (const float*)d_in[9];
    const float *W2l = (const float*)d_in[10], *b2l = (const float*)d_in[11];
    const float *W2r = (const float*)d_in[12], *b2r = (const float*)d_in[13];
    const float *W2e = (const float*)d_in[14], *att2 = (const float*)d_in[15], *bias2 = (const float*)d_in[16];
    const float *Wc1 = (const float*)d_in[17], *bc1 = (const float*)d_in[18];
    const float *Wc2 = (const float*)d_in[19], *bc2 = (const float*)d_in[20];
    const float *Ws1 = (const float*)d_in[21], *bs1 = (const float*)d_in[22];
    const float *Ws2 = (const float*)d_in[23], *bs2 = (const float*)d_in[24];
    const float *Wn1 = (const float*)d_in[25], *bn1 = (const float*)d_in[26];
    const float *Wn2 = (const float*)d_in[27], *bn2 = (const float*)d_in[28];
    float* out = (float*)d_out;

    if (d_ws == nullptr || ws_size < WS_NEED) {
        // fallback: proven monolith (142.6 us rocprof)
        planetwars_gnn_mono<<<dim3(NB), dim3(512), 0, stream>>>(
            x, eattr, W1l, b1l, W1r, b1r, W1e, att1, bias1,
            W2l, b2l, W2r, b2r, W2e, att2, bias2,
            Wc1, bc1, Wc2, bc2, Ws1, bs1, Ws2, bs2, Wn1, bn1, Wn2, bn2, out);
        return;
    }

    float* B0 = (float*)d_ws;                 // xl (layer1 then layer2 messages)
    float* B1 = B0 + WS_SLOT;                 // xr
    float* B2 = B0 + 2 * (long)WS_SLOT;       // h

    k_t1   <<<dim3(NN * 128 / 256), dim3(256), 0, stream>>>(x, W1l, b1l, W1r, b1r, B0, B1);
    k_attn <<<dim3(NB * 2),         dim3(512), 0, stream>>>(B0, B1, eattr, W1e, att1, bias1, B2, 0);
    k_norm <<<dim3(NB * DD * 4 / 256), dim3(256), 0, stream>>>(B2);
    k_t2   <<<dim3(NB * 2),         dim3(512), 0, stream>>>(B2, W2l, b2l, W2r, b2r, B0, B1);
    k_attn <<<dim3(NB * 2),         dim3(512), 0, stream>>>(B0, B1, eattr, W2e, att2, bias2, B2, 1);
    k_heads<<<dim3(NB),             dim3(512), 0, stream>>>(B2, Wc1, bc1, Wc2, bc2,
                                                            Ws1, bs1, Ws2, bs2,
                                                            Wn1, bn1, Wn2, bn2, out);
}

// Round 11
// 311.962 us; speedup vs baseline: 1.1956x; 1.0650x over previous
//
#include <hip/hip_runtime.h>

#define PP    32      // nodes per graph
#define FF    16      // input features
#define HH    4       // heads
#define CC    32      // head dim
#define DD    128     // hidden (H*C)
#define EDIM  5
#define EPG   992     // edges per graph = P*(P-1)
#define NB    512     // graphs
#define NN    (NB * PP)                 // 16384 nodes
// workspace slots (floats): 3 x 8 MiB
#define WS_SLOT 2097152
#define WS_NEED ((size_t)3 * WS_SLOT * 4)

// ---- DPP helpers (HW-validated R4) ------------------------------------------
template <int CTRL>
__device__ __forceinline__ float dpp_add(float v) {
    int t = __builtin_amdgcn_update_dpp(0, __builtin_bit_cast(int, v), CTRL, 0xF, 0xF, true);
    return v + __builtin_bit_cast(float, t);
}
template <int CTRL>
__device__ __forceinline__ float dpp_mov(float v) {
    int t = __builtin_amdgcn_update_dpp(0, __builtin_bit_cast(int, v), CTRL, 0xF, 0xF, true);
    return __builtin_bit_cast(float, t);
}
__device__ __forceinline__ float red64(float v) {
    v = dpp_add<0x111>(v); v = dpp_add<0x112>(v); v = dpp_add<0x114>(v);
    v = dpp_add<0x118>(v); v = dpp_add<0x142>(v); v = dpp_add<0x143>(v);
    return v;                            // lane 63 holds the 64-lane sum
}
__device__ __forceinline__ float redquad(float v) {
    v = dpp_add<0xB1>(v);                // quad_perm [1,0,3,2]
    v = dpp_add<0x4E>(v);                // quad_perm [2,3,0,1]
    return v;
}
__device__ __forceinline__ float maxquad(float v) {
    v = fmaxf(v, dpp_mov<0xB1>(v));
    v = fmaxf(v, dpp_mov<0x4E>(v));
    return v;
}

// ---- shared attention phases (score/softmax/agg), monolith-proven bodies ----
// sMsg/sDst may live in LDS or global; FMA order identical everywhere.
__device__ __forceinline__ void attn_score(const float* __restrict__ sMsg, int msgStride,
                                           const float* __restrict__ sDst, int dstStride,
                                           const float* __restrict__ eattr, long eBase,
                                           const float* __restrict__ We, const float* __restrict__ att,
                                           float* __restrict__ sS, int tid, int d0)
{
    const int s   = tid >> 4;
    const int h4  = (tid >> 2) & 3;
    const int ch0 = (tid & 15) * 8;
    float we[40], at[8], xlv[8];
#pragma unroll
    for (int q = 0; q < 10; ++q)
        *(float4*)(we + q * 4) = *(const float4*)(We + ch0 * EDIM + q * 4);
    *(float4*)(at)      = *(const float4*)(att + ch0);
    *(float4*)(at + 4)  = *(const float4*)(att + ch0 + 4);
    *(float4*)(xlv)     = *(const float4*)(sMsg + (long)s * msgStride + ch0);
    *(float4*)(xlv + 4) = *(const float4*)(sMsg + (long)s * msgStride + ch0 + 4);

    for (int dl = 0; dl < 16; ++dl) {
        const int d = d0 + dl;
        int jj = d - (d > s);
        if (jj > 30) jj = 30;                         // d==s==31 clamp (discarded)
        const float* ea = eattr + (eBase + s * 31 + jj) * EDIM;
        const float e0 = ea[0], e1 = ea[1], e2 = ea[2], e3 = ea[3], e4 = ea[4];
        float xrv[8];
        *(float4*)(xrv)     = *(const float4*)(sDst + (long)d * dstStride + ch0);
        *(float4*)(xrv + 4) = *(const float4*)(sDst + (long)d * dstStride + ch0 + 4);
        float acc0 = 0.f, acc1 = 0.f;
#pragma unroll
        for (int c = 0; c < 8; ++c) {
            float v = xlv[c] + xrv[c];
            const float* w = we + c * EDIM;
            v = fmaf(w[0], e0, v); v = fmaf(w[1], e1, v); v = fmaf(w[2], e2, v);
            v = fmaf(w[3], e3, v); v = fmaf(w[4], e4, v);
            v = fmaf(0.4f, fabsf(v), 0.6f * v);       // leaky_relu(., 0.2)
            if (c & 1) acc1 = fmaf(v, at[c], acc1);
            else       acc0 = fmaf(v, at[c], acc0);
        }
        const float r = redquad(acc0 + acc1);         // sum over 4 c4-chunks
        if ((tid & 3) == 0)
            sS[s * 64 + dl * 4 + h4] = r;
    }
}

__device__ __forceinline__ void attn_softmax(float* __restrict__ sS, int tid, int d0)
{
    if (tid < 256) {
        const int col = tid >> 2;                     // dl*4 + h
        const int r   = tid & 3;
        const int dd  = d0 + (col >> 2);              // destination node
        float v[8];
        float mx = -3.4e38f;
#pragma unroll
        for (int i = 0; i < 8; ++i) {
            const int s = r * 8 + i;
            v[i] = sS[s * 64 + col];
            mx = (s == dd) ? mx : fmaxf(mx, v[i]);
        }
        mx = maxquad(mx);
        float sum = 0.f;
#pragma unroll
        for (int i = 0; i < 8; ++i) {
            const int s = r * 8 + i;
            float ex = __expf(v[i] - mx);
            ex = (s == dd) ? 0.f : ex;                // diagonal forced to 0
            v[i] = ex; sum += ex;
        }
        sum = redquad(sum);
        const float inv = 1.f / (sum + 1e-16f);
#pragma unroll
        for (int i = 0; i < 8; ++i)
            sS[(r * 8 + i) * 64 + col] = v[i] * inv;
    }
}

__device__ __forceinline__ void attn_agg(const float* __restrict__ sS,
                                         const float* __restrict__ msg, int msgStride,
                                         const float* __restrict__ bias,
                                         float* __restrict__ hout, long outBase,
                                         int tid, int d0, int relu)
{
    const int dl = tid >> 5, ch4 = tid & 31;
    const int col = dl * 4 + (ch4 >> 3);
    const float* bp = bias + ch4 * 4;
    float4 acc = make_float4(bp[0], bp[1], bp[2], bp[3]);
#pragma unroll
    for (int s = 0; s < PP; ++s) {
        const float a = sS[s * 64 + col];             // alpha(d==s) == 0
        const float4 xv = *(const float4*)(msg + (long)s * msgStride + ch4 * 4);
        acc.x = fmaf(a, xv.x, acc.x);
        acc.y = fmaf(a, xv.y, acc.y);
        acc.z = fmaf(a, xv.z, acc.z);
        acc.w = fmaf(a, xv.w, acc.w);
    }
    if (relu) {
        acc.x = fmaxf(acc.x, 0.f); acc.y = fmaxf(acc.y, 0.f);
        acc.z = fmaxf(acc.z, 0.f); acc.w = fmaxf(acc.w, 0.f);
    }
    *(float4*)(hout + (outBase + d0 + dl) * DD + ch4 * 4) = acc;
}

// =============================================================================
// Pipeline kernels
// Buffers: B0 = xl2, B1 = xr2, B2 = h (h1 -> h1n -> h2).
// =============================================================================

// ---- K_L1: fused layer-1 (T1 + score + softmax + agg) per (graph, d-half). --
// 1024 blocks x 512 thr, 40 KB LDS.  T1 recomputed per d-half (1.3 us total
// work, duplication negligible) -> kills k_t1 dispatch + xl1/xr1 round-trip.
extern "C" __global__ void __launch_bounds__(512, 4)
k_l1(const float* __restrict__ x, const float* __restrict__ eattr,
     const float* __restrict__ W1l, const float* __restrict__ b1l,
     const float* __restrict__ W1r, const float* __restrict__ b1r,
     const float* __restrict__ We, const float* __restrict__ att,
     const float* __restrict__ bias,
     float* __restrict__ hout)
{
    __shared__ __align__(16) float sA[PP * DD];       // xl1   (16 KB)
    __shared__ __align__(16) float sB[PP * DD];       // xr1   (16 KB)
    __shared__ __align__(16) float sS[PP * 64];       // x | scores (8 KB)
    const int b = blockIdx.x;
    const int g = b >> 1, d0 = (b & 1) * 16;
    const int tid = threadIdx.x;
    const long eBase = (long)g * EPG;

    // stage x tile (32x16 = 512 floats) into sS
    sS[tid] = x[g * PP * FF + tid];
    __syncthreads();

    // T1 (monolith body): j = tid&127, 8 rows each; reads sS-as-x
    {
        const int j = tid & 127, r0 = (tid >> 7) * 8;
        float wl[16], wr[16];
#pragma unroll
        for (int q = 0; q < 4; ++q) {
            *(float4*)(wl + q * 4) = *(const float4*)(W1l + j * FF + q * 4);
            *(float4*)(wr + q * 4) = *(const float4*)(W1r + j * FF + q * 4);
        }
        const float bl = b1l[j], br = b1r[j];
#pragma unroll
        for (int i = 0; i < 8; ++i) {
            const float* xv = sS + (r0 + i) * FF;
            float al = bl, ar = br;
#pragma unroll
            for (int k = 0; k < FF; ++k) {
                const float xk = xv[k];
                al = fmaf(wl[k], xk, al);
                ar = fmaf(wr[k], xk, ar);
            }
            sA[(r0 + i) * DD + j] = al;
            sB[(r0 + i) * DD + j] = ar;
        }
    }
    __syncthreads();

    attn_score(sA, DD, sB, DD, eattr, eBase, We, att, sS, tid, d0);
    __syncthreads();
    attn_softmax(sS, tid, d0);
    __syncthreads();
    attn_agg(sS, sA, DD, bias, hout, (long)g * PP, tid, d0, 0);
}

// ---- K_NORM: MeanSubtractionNorm + ReLU in place.  quad per (g, col). ------
extern "C" __global__ void __launch_bounds__(256, 4)
k_norm(float* __restrict__ h)
{
    const int idx = blockIdx.x * 256 + threadIdx.x;
    const int colg = idx >> 2;                        // g*128 + col
    const int r = idx & 3;
    const int g = colg >> 7, col = colg & 127;
    float v[8];
    float ssum = 0.f;
#pragma unroll
    for (int i = 0; i < 8; ++i) {
        v[i] = h[(long)(g * PP + r * 8 + i) * DD + col];
        ssum += v[i];
    }
    ssum = redquad(ssum);
    const float mn = ssum * (1.0f / 32.0f);
#pragma unroll
    for (int i = 0; i < 8; ++i)
        h[(long)(g * PP + r * 8 + i) * DD + col] = fmaxf(v[i] - mn, 0.f);
}

// ---- K_T2: layer-2 node transforms per (graph, node-half). -----------------
// 1024 blocks x 512 thr (32 waves/CU).  Thread = one j (both L and R) over
// 4 rows -> 8 accumulators; #pragma unroll 2 batches 8 weight-float4 loads
// in flight (R10's serial 4-load/iter schedule at VGPR=36 was the 81 us stall).
// Per-output FMA order identical to monolith.
extern "C" __global__ void __launch_bounds__(512, 4)
k_t2(const float* __restrict__ h,
     const float* __restrict__ W2l, const float* __restrict__ b2l,
     const float* __restrict__ W2r, const float* __restrict__ b2r,
     float* __restrict__ xl, float* __restrict__ xr)
{
    __shared__ __align__(16) float sH[16 * DD];       // 8 KB (16 nodes)
    const int b = blockIdx.x;
    const int g = b >> 1, nh = (b & 1) * 16;
    const int tid = threadIdx.x;
    // stage 16 node rows (2048 floats): one float4 per thread
    {
        const float* hb = h + ((long)g * PP + nh) * DD;
        *(float4*)(sH + tid * 4) = *(const float4*)(hb + tid * 4);
    }
    __syncthreads();

    const int j = tid & 127, r4 = tid >> 7;           // 4 rows: r4*4 .. r4*4+3
    float accL[4], accR[4];
    const float bl = b2l[j], br = b2r[j];
#pragma unroll
    for (int i = 0; i < 4; ++i) { accL[i] = bl; accR[i] = br; }
    const float* WL = W2l + j * DD;
    const float* WR = W2r + j * DD;
#pragma unroll 2
    for (int k8 = 0; k8 < 16; ++k8) {
        const float4 l0 = *(const float4*)(WL + k8 * 8), l1 = *(const float4*)(WL + k8 * 8 + 4);
        const float4 r0 = *(const float4*)(WR + k8 * 8), r1 = *(const float4*)(WR + k8 * 8 + 4);
#pragma unroll
        for (int i = 0; i < 4; ++i) {
            const float4 a0 = *(const float4*)(sH + (r4 * 4 + i) * DD + k8 * 8);
            const float4 a1 = *(const float4*)(sH + (r4 * 4 + i) * DD + k8 * 8 + 4);
            accL[i] = fmaf(l0.x, a0.x, accL[i]); accL[i] = fmaf(l0.y, a0.y, accL[i]);
            accL[i] = fmaf(l0.z, a0.z, accL[i]); accL[i] = fmaf(l0.w, a0.w, accL[i]);
            accL[i] = fmaf(l1.x, a1.x, accL[i]); accL[i] = fmaf(l1.y, a1.y, accL[i]);
            accL[i] = fmaf(l1.z, a1.z, accL[i]); accL[i] = fmaf(l1.w, a1.w, accL[i]);
            accR[i] = fmaf(r0.x, a0.x, accR[i]); accR[i] = fmaf(r0.y, a0.y, accR[i]);
            accR[i] = fmaf(r0.z, a0.z, accR[i]); accR[i] = fmaf(r0.w, a0.w, accR[i]);
            accR[i] = fmaf(r1.x, a1.x, accR[i]); accR[i] = fmaf(r1.y, a1.y, accR[i]);
            accR[i] = fmaf(r1.z, a1.z, accR[i]); accR[i] = fmaf(r1.w, a1.w, accR[i]);
        }
    }
#pragma unroll
    for (int i = 0; i < 4; ++i) {
        xl[((long)g * PP + nh + r4 * 4 + i) * DD + j] = accL[i];
        xr[((long)g * PP + nh + r4 * 4 + i) * DD + j] = accR[i];
    }
}

// ---- K_ATTN: layer-2 attention per (graph, d-half).  xl/xr from global. ----
extern "C" __global__ void __launch_bounds__(512, 4)
k_attn(const float* __restrict__ xl, const float* __restrict__ xr,
       const float* __restrict__ eattr,
       const float* __restrict__ We, const float* __restrict__ att,
       const float* __restrict__ bias,
       float* __restrict__ hout, const int relu)
{
    __shared__ __align__(16) float sS[PP * 64];       // 8 KB
    const int b = blockIdx.x;
    const int g = b >> 1, d0 = (b & 1) * 16;
    const int tid = threadIdx.x;
    const long eBase = (long)g * EPG;

    attn_score(xl + (long)g * PP * DD, DD, xr + (long)g * PP * DD, DD,
               eattr, eBase, We, att, sS, tid, d0);
    __syncthreads();
    attn_softmax(sS, tid, d0);
    __syncthreads();
    attn_agg(sS, xl + (long)g * PP * DD, DD, bias, hout, (long)g * PP, tid, d0, relu);
}

// ---- K_HEADS: pool + heads.  per-graph 512-thr block, LDS-staged h2. -------
extern "C" __global__ void __launch_bounds__(512, 4)
k_heads(const float* __restrict__ h2,
        const float* __restrict__ Wc1, const float* __restrict__ bc1,
        const float* __restrict__ Wc2, const float* __restrict__ bc2,
        const float* __restrict__ Ws1, const float* __restrict__ bs1,
        const float* __restrict__ Ws2, const float* __restrict__ bs2,
        const float* __restrict__ Wn1, const float* __restrict__ bn1,
        const float* __restrict__ Wn2, const float* __restrict__ bn2,
        float* __restrict__ out)
{
    __shared__ __align__(16) float sH[PP * DD];       // 16 KB
    __shared__ __align__(16) float sU[DD];
    const int g = blockIdx.x, tid = threadIdx.x;
    {
        const float* hb = h2 + (long)g * PP * DD;
        *(float4*)(sH + tid * 8)     = *(const float4*)(hb + tid * 8);
        *(float4*)(sH + tid * 8 + 4) = *(const float4*)(hb + tid * 8 + 4);
    }
    __syncthreads();

    // ---- global mean pool -> sU[0..127]
    {
        const int col = tid >> 2, r = tid & 3;
        float ssum = 0.f;
#pragma unroll
        for (int i = 0; i < 8; ++i) ssum += sH[(r * 8 + i) * DD + col];
        ssum = redquad(ssum);
        if (r == 0) sU[col] = ssum * (1.0f / 32.0f);
    }
    __syncthreads();

    // ---- source-actor: fused Ws1-GEMM + Ws2 dot
    {
        const int jj = tid & 63, d0 = (tid >> 6) * 4;
        const float b0 = bs1[jj], b1 = bs1[jj + 64];
        float acc0[4], acc1[4];
#pragma unroll
        for (int i = 0; i < 4; ++i) { acc0[i] = b0; acc1[i] = b1; }
        const float* W0 = Ws1 + jj * DD;
        const float* W1 = Ws1 + (jj + 64) * DD;
        for (int k8 = 0; k8 < 16; ++k8) {
            const float4 w00 = *(const float4*)(W0 + k8 * 8), w01 = *(const float4*)(W0 + k8 * 8 + 4);
            const float4 w10 = *(const float4*)(W1 + k8 * 8), w11 = *(const float4*)(W1 + k8 * 8 + 4);
#pragma unroll
            for (int i = 0; i < 4; ++i) {
                const float4 a0 = *(const float4*)(sH + (d0 + i) * DD + k8 * 8);
                const float4 a1 = *(const float4*)(sH + (d0 + i) * DD + k8 * 8 + 4);
                acc0[i] = fmaf(w00.x, a0.x, acc0[i]); acc0[i] = fmaf(w00.y, a0.y, acc0[i]);
                acc0[i] = fmaf(w00.z, a0.z, acc0[i]); acc0[i] = fmaf(w00.w, a0.w, acc0[i]);
                acc0[i] = fmaf(w01.x, a1.x, acc0[i]); acc0[i] = fmaf(w01.y, a1.y, acc0[i]);
                acc0[i] = fmaf(w01.z, a1.z, acc0[i]); acc0[i] = fmaf(w01.w, a1.w, acc0[i]);
                acc1[i] = fmaf(w10.x, a0.x, acc1[i]); acc1[i] = fmaf(w10.y, a0.y, acc1[i]);
                acc1[i] = fmaf(w10.z, a0.z, acc1[i]); acc1[i] = fmaf(w10.w, a0.w, acc1[i]);
                acc1[i] = fmaf(w11.x, a1.x, acc1[i]); acc1[i] = fmaf(w11.y, a1.y, acc1[i]);
                acc1[i] = fmaf(w11.z, a1.z, acc1[i]); acc1[i] = fmaf(w11.w, a1.w, acc1[i]);
            }
        }
        const float ws2a = Ws2[jj], ws2b = Ws2[jj + 64];
        const float bias2s = bs2[0];
#pragma unroll
        for (int i = 0; i < 4; ++i) {
            const float t = fmaf(fmaxf(acc0[i], 0.f), ws2a, fmaxf(acc1[i], 0.f) * ws2b);
            const float r = red64(t);                 // lane 63 holds node logit
            if ((tid & 63) == 63) out[g * 34 + 2 + d0 + i] = r + bias2s;
        }
    }

    // ---- value / noop: wave 0 = critic, wave 1 = noop
    if (tid < 128) {
        const int w = tid >> 6, j = tid & 63;
        const float* Wa = (w ? Wn1 : Wc1);
        const float* ba = (w ? bn1 : bc1);
        const float* Wb = (w ? Wn2 : Wc2);
        const float  bb = (w ? bn2 : bc2)[0];
        float h0 = ba[j], h1 = ba[j + 64];
        const float* R0 = Wa + j * DD;
        const float* R1 = Wa + (j + 64) * DD;
#pragma unroll
        for (int k8 = 0; k8 < 16; ++k8) {
            const float4 g0 = *(const float4*)(sU + k8 * 8);
            const float4 g1 = *(const float4*)(sU + k8 * 8 + 4);
            const float4 p00 = *(const float4*)(R0 + k8 * 8), p01 = *(const float4*)(R0 + k8 * 8 + 4);
            const float4 p10 = *(const float4*)(R1 + k8 * 8), p11 = *(const float4*)(R1 + k8 * 8 + 4);
            h0 = fmaf(p00.x, g0.x, h0); h0 = fmaf(p00.y, g0.y, h0);
            h0 = fmaf(p00.z, g0.z, h0); h0 = fmaf(p00.w, g0.w, h0);
            h0 = fmaf(p01.x, g1.x, h0); h0 = fmaf(p01.y, g1.y, h0);
            h0 = fmaf(p01.z, g1.z, h0); h0 = fmaf(p01.w, g1.w, h0);
            h1 = fmaf(p10.x, g0.x, h1); h1 = fmaf(p10.y, g0.y, h1);
            h1 = fmaf(p10.z, g0.z, h1); h1 = fmaf(p10.w, g0.w, h1);
            h1 = fmaf(p11.x, g1.x, h1); h1 = fmaf(p11.y, g1.y, h1);
            h1 = fmaf(p11.z, g1.z, h1); h1 = fmaf(p11.w, g1.w, h1);
        }
        const float t = fmaf(fmaxf(h0, 0.f), Wb[j], fmaxf(h1, 0.f) * Wb[j + 64]);
        const float r = red64(t);
        if (j == 63) out[g * 34 + w] = r + bb;
    }
}

// =============================================================================
// Fallback monolith (R8 source, proven 142.6 us) — used only if ws too small.
// =============================================================================
__device__ __forceinline__ void mono_attention(const float* __restrict__ eattr,
                                          const float* __restrict__ We, const float* __restrict__ att,
                                          const float* __restrict__ bias,
                                          const float* __restrict__ sMsg, const float* __restrict__ sDst,
                                          float* __restrict__ sS, float* __restrict__ sOut,
                                          int tid, long eBase, bool relu)
{
    float* __restrict__ sE = sOut;
    {
        const int s  = tid >> 4;
        const int ch0 = (tid & 15) * 8;
        float we[40], at[8], xl[8];
#pragma unroll
        for (int q = 0; q < 10; ++q)
            *(float4*)(we + q * 4) = *(const float4*)(We + ch0 * EDIM + q * 4);
        *(float4*)(at)     = *(const float4*)(att + ch0);
        *(float4*)(at + 4) = *(const float4*)(att + ch0 + 4);
        *(float4*)(xl)     = *(const float4*)(sMsg + s * DD + ch0);
        *(float4*)(xl + 4) = *(const float4*)(sMsg + s * DD + ch0 + 4);
        for (int halfd = 0; halfd < 2; ++halfd) {
            const int d0 = halfd * 16;
            {
                const int dl = tid & 15;
                const int d = d0 + dl;
                int jj = d - (d > s);
                if (jj > 30) jj = 30;
                const float* ea = eattr + (eBase + s * 31 + jj) * EDIM;
                const float e0 = ea[0], e1 = ea[1], e2 = ea[2], e3 = ea[3], e4 = ea[4];
                float* p = sE + (((s << 4) | dl) << 3);
                *(float4*)p = make_float4(e0, e1, e2, e3);
                p[4] = e4;
            }
            __syncthreads();
            for (int dl = 0; dl < 16; ++dl) {
                const int d = d0 + dl;
                const float* ep = sE + (((s << 4) | dl) << 3);
                const float4 ef = *(const float4*)ep;
                const float e4v = ep[4];
                float xr[8];
                *(float4*)(xr)     = *(const float4*)(sDst + d * DD + ch0);
                *(float4*)(xr + 4) = *(const float4*)(sDst + d * DD + ch0 + 4);
                float acc0 = 0.f, acc1 = 0.f;
#pragma unroll
                for (int c = 0; c < 8; ++c) {
                    float v = xl[c] + xr[c];
                    const float* w = we + c * EDIM;
                    v = fmaf(w[0], ef.x, v); v = fmaf(w[1], ef.y, v); v = fmaf(w[2], ef.z, v);
                    v = fmaf(w[3], ef.w, v); v = fmaf(w[4], e4v, v);
                    v = fmaf(0.4f, fabsf(v), 0.6f * v);
                    if (c & 1) acc1 = fmaf(v, at[c], acc1);
                    else       acc0 = fmaf(v, at[c], acc0);
                }
                const float r = redquad(acc0 + acc1);
                if ((tid & 3) == 0)
                    sS[s * DD + d * HH + ((tid >> 2) & 3)] = r;
            }
            __syncthreads();
        }
    }
    {
        const int col = tid >> 2;
        const int r   = tid & 3;
        const int dd  = col >> 2;
        float v[8];
        float mx = -3.4e38f;
#pragma unroll
        for (int i = 0; i < 8; ++i) {
            const int s = r * 8 + i;
            v[i] = sS[s * DD + col];
            mx = (s == dd) ? mx : fmaxf(mx, v[i]);
        }
        mx = maxquad(mx);
        float sum = 0.f;
#pragma unroll
        for (int i = 0; i < 8; ++i) {
            const int s = r * 8 + i;
            float ex = __expf(v[i] - mx);
            ex = (s == dd) ? 0.f : ex;
            v[i] = ex; sum += ex;
        }
        sum = redquad(sum);
        const float inv = 1.f / (sum + 1e-16f);
#pragma unroll
        for (int i = 0; i < 8; ++i)
            sS[(r * 8 + i) * DD + col] = v[i] * inv;
    }
    __syncthreads();
    {
        const int d = tid >> 4, sub = tid & 15;
#pragma unroll
        for (int half = 0; half < 2; ++half) {
            const int ch4 = half * 16 + sub;
            const int idx = d * HH + (ch4 >> 3);
            const float* bp = bias + ch4 * 4;
            float4 acc = make_float4(bp[0], bp[1], bp[2], bp[3]);
#pragma unroll
            for (int s = 0; s < PP; ++s) {
                const float a = sS[s * DD + idx];
                const float4 xv = *(const float4*)(sMsg + s * DD + ch4 * 4);
                acc.x = fmaf(a, xv.x, acc.x);
                acc.y = fmaf(a, xv.y, acc.y);
                acc.z = fmaf(a, xv.z, acc.z);
                acc.w = fmaf(a, xv.w, acc.w);
            }
            if (relu) {
                acc.x = fmaxf(acc.x, 0.f); acc.y = fmaxf(acc.y, 0.f);
                acc.z = fmaxf(acc.z, 0.f); acc.w = fmaxf(acc.w, 0.f);
            }
            *(float4*)(sOut + d * DD + ch4 * 4) = acc;
        }
    }
}

extern "C" __global__ void __launch_bounds__(512)
planetwars_gnn_mono(const float* __restrict__ x, const float* __restrict__ eattr,
                    const float* __restrict__ W1l, const float* __restrict__ b1l,
                    const float* __restrict__ W1r, const float* __restrict__ b1r,
                    const float* __restrict__ W1e, const float* __restrict__ att1, const float* __restrict__ bias1,
                    const float* __restrict__ W2l, const float* __restrict__ b2l,
                    const float* __restrict__ W2r, const float* __restrict__ b2r,
                    const float* __restrict__ W2e, const float* __restrict__ att2, const float* __restrict__ bias2,
                    const float* __restrict__ Wc1, const float* __restrict__ bc1,
                    const float* __restrict__ Wc2, const float* __restrict__ bc2,
                    const float* __restrict__ Ws1, const float* __restrict__ bs1,
                    const float* __restrict__ Ws2, const float* __restrict__ bs2,
                    const float* __restrict__ Wn1, const float* __restrict__ bn1,
                    const float* __restrict__ Wn2, const float* __restrict__ bn2,
                    float* __restrict__ out)
{
    __shared__ __align__(16) float sA[PP * DD];
    __shared__ __align__(16) float sB[PP * DD];
    __shared__ __align__(16) float sH[PP * DD];
    __shared__ __align__(16) float sU[PP * DD];
    const int tid = threadIdx.x;
    const int g = blockIdx.x;
    const long eBase = (long)g * EPG;
    sU[tid] = x[g * PP * FF + tid];
    __syncthreads();
    {
        const int j = tid & 127, d0 = (tid >> 7) * 8;
        float wl[16], wr[16];
#pragma unroll
        for (int q = 0; q < 4; ++q) {
            *(float4*)(wl + q * 4) = *(const float4*)(W1l + j * FF + q * 4);
            *(float4*)(wr + q * 4) = *(const float4*)(W1r + j * FF + q * 4);
        }
        const float bl = b1l[j], br = b1r[j];
#pragma unroll
        for (int i = 0; i < 8; ++i) {
            const float* xr = sU + (d0 + i) * FF;
            float al = bl, ar = br;
#pragma unroll
            for (int k = 0; k < FF; ++k) {
                const float xv = xr[k];
                al = fmaf(wl[k], xv, al);
                ar = fmaf(wr[k], xv, ar);
            }
            sA[(d0 + i) * DD + j] = al;
            sB[(d0 + i) * DD + j] = ar;
        }
    }
    __syncthreads();
    mono_attention(eattr, W1e, att1, bias1, sA, sB, sU, sH, tid, eBase, false);
    __syncthreads();
    {
        const int col = tid >> 2, r = tid & 3;
        float v[8];
        float ssum = 0.f;
#pragma unroll
        for (int i = 0; i < 8; ++i) {
            v[i] = sH[(r * 8 + i) * DD + col];
            ssum += v[i];
        }
        ssum = redquad(ssum);
        const float mn = ssum * (1.0f / 32.0f);
#pragma unroll
        for (int i = 0; i < 8; ++i)
            sH[(r * 8 + i) * DD + col] = fmaxf(v[i] - mn, 0.f);
    }
    __syncthreads();
    {
        const int jj = tid & 63, d0 = (tid >> 6) * 4;
        float accL0[4], accL1[4], accR0[4], accR1[4];
        const float bl0 = b2l[jj], bl1 = b2l[jj + 64];
        const float br0 = b2r[jj], br1 = b2r[jj + 64];
#pragma unroll
        for (int i = 0; i < 4; ++i) { accL0[i] = bl0; accL1[i] = bl1; accR0[i] = br0; accR1[i] = br1; }
        const float* WL0 = W2l + jj * DD;
        const float* WL1 = W2l + (jj + 64) * DD;
        const float* WR0 = W2r + jj * DD;
        const float* WR1 = W2r + (jj + 64) * DD;
        for (int k8 = 0; k8 < 16; ++k8) {
            const float4 l00 = *(const float4*)(WL0 + k8 * 8), l01 = *(const float4*)(WL0 + k8 * 8 + 4);
            const float4 l10 = *(const float4*)(WL1 + k8 * 8), l11 = *(const float4*)(WL1 + k8 * 8 + 4);
            const float4 r00 = *(const float4*)(WR0 + k8 * 8), r01 = *(const float4*)(WR0 + k8 * 8 + 4);
            const float4 r10 = *(const float4*)(WR1 + k8 * 8), r11 = *(const float4*)(WR1 + k8 * 8 + 4);
#pragma unroll
            for (int i = 0; i < 4; ++i) {
                const float4 a0 = *(const float4*)(sH + (d0 + i) * DD + k8 * 8);
                const float4 a1 = *(const float4*)(sH + (d0 + i) * DD + k8 * 8 + 4);
                accL0[i] = fmaf(l00.x, a0.x, accL0[i]); accL0[i] = fmaf(l00.y, a0.y, accL0[i]);
                accL0[i] = fmaf(l00.z, a0.z, accL0[i]); accL0[i] = fmaf(l00.w, a0.w, accL0[i]);
                accL0[i] = fmaf(l01.x, a1.x, accL0[i]); accL0[i] = fmaf(l01.y, a1.y, accL0[i]);
                accL0[i] = fmaf(l01.z, a1.z, accL0[i]); accL0[i] = fmaf(l01.w, a1.w, accL0[i]);
                accL1[i] = fmaf(l10.x, a0.x, accL1[i]); accL1[i] = fmaf(l10.y, a0.y, accL1[i]);
                accL1[i] = fmaf(l10.z, a0.z, accL1[i]); accL1[i] = fmaf(l10.w, a0.w, accL1[i]);
                accL1[i] = fmaf(l11.x, a1.x, accL1[i]); accL1[i] = fmaf(l11.y, a1.y, accL1[i]);
                accL1[i] = fmaf(l11.z, a1.z, accL1[i]); accL1[i] = fmaf(l11.w, a1.w, accL1[i]);
                accR0[i] = fmaf(r00.x, a0.x, accR0[i]); accR0[i] = fmaf(r00.y, a0.y, accR0[i]);
                accR0[i] = fmaf(r00.z, a0.z, accR0[i]); accR0[i] = fmaf(r00.w, a0.w, accR0[i]);
                accR0[i] = fmaf(r01.x, a1.x, accR0[i]); accR0[i] = fmaf(r01.y, a1.y, accR0[i]);
                accR0[i] = fmaf(r01.z, a1.z, accR0[i]); accR0[i] = fmaf(r01.w, a1.w, accR0[i]);
                accR1[i] = fmaf(r10.x, a0.x, accR1[i]); accR1[i] = fmaf(r10.y, a0.y, accR1[i]);
                accR1[i] = fmaf(r10.z, a0.z, accR1[i]); accR1[i] = fmaf(r10.w, a0.w, accR1[i]);
                accR1[i] = fmaf(r11.x, a1.x, accR1[i]); accR1[i] = fmaf(r11.y, a1.y, accR1[i]);
                accR1[i] = fmaf(r11.z, a1.z, accR1[i]); accR1[i] = fmaf(r11.w, a1.w, accR1[i]);
            }
        }
#pragma unroll
        for (int i = 0; i < 4; ++i) {
            sA[(d0 + i) * DD + jj]      = accL0[i];
            sA[(d0 + i) * DD + jj + 64] = accL1[i];
            sB[(d0 + i) * DD + jj]      = accR0[i];
            sB[(d0 + i) * DD + jj + 64] = accR1[i];
        }
    }
    __syncthreads();
    mono_attention(eattr, W2e, att2, bias2, sA, sB, sU, sH, tid, eBase, true);
    __syncthreads();
    {
        const int col = tid >> 2, r = tid & 3;
        float ssum = 0.f;
#pragma unroll
        for (int i = 0; i < 8; ++i) ssum += sH[(r * 8 + i) * DD + col];
        ssum = redquad(ssum);
        if (r == 0) sU[col] = ssum * (1.0f / 32.0f);
    }
    __syncthreads();
    {
        const int jj = tid & 63, d0 = (tid >> 6) * 4;
        const float b0 = bs1[jj], b1 = bs1[jj + 64];
        float acc0[4], acc1[4];
#pragma unroll
        for (int i = 0; i < 4; ++i) { acc0[i] = b0; acc1[i] = b1; }
        const float* W0 = Ws1 + jj * DD;
        const float* W1 = Ws1 + (jj + 64) * DD;
        for (int k8 = 0; k8 < 16; ++k8) {
            const float4 w00 = *(const float4*)(W0 + k8 * 8), w01 = *(const float4*)(W0 + k8 * 8 + 4);
            const float4 w10 = *(const float4*)(W1 + k8 * 8), w11 = *(const float4*)(W1 + k8 * 8 + 4);
#pragma unroll
            for (int i = 0; i < 4; ++i) {
                const float4 a0 = *(const float4*)(sH + (d0 + i) * DD + k8 * 8);
                const float4 a1 = *(const float4*)(sH + (d0 + i) * DD + k8 * 8 + 4);
                acc0[i] = fmaf(w00.x, a0.x, acc0[i]); acc0[i] = fmaf(w00.y, a0.y, acc0[i]);
                acc0[i] = fmaf(w00.z, a0.z, acc0[i]); acc0[i] = fmaf(w00.w, a0.w, acc0[i]);
                acc0[i] = fmaf(w01.x, a1.x, acc0[i]); acc0[i] = fmaf(w01.y, a1.y, acc0[i]);
                acc0[i] = fmaf(w01.z, a1.z, acc0[i]); acc0[i] = fmaf(w01.w, a1.w, acc0[i]);
                acc1[i] = fmaf(w10.x, a0.x, acc1[i]); acc1[i] = fmaf(w10.y, a0.y, acc1[i]);
                acc1[i] = fmaf(w10.z, a0.z, acc1[i]); acc1[i] = fmaf(w10.w, a0.w, acc1[i]);
                acc1[i] = fmaf(w11.x, a1.x, acc1[i]); acc1[i] = fmaf(w11.y, a1.y, acc1[i]);
                acc1[i] = fmaf(w11.z, a1.z, acc1[i]); acc1[i] = fmaf(w11.w, a1.w, acc1[i]);
            }
        }
        const float ws2a = Ws2[jj], ws2b = Ws2[jj + 64];
        const float bias2s = bs2[0];
#pragma unroll
        for (int i = 0; i < 4; ++i) {
            const float t = fmaf(fmaxf(acc0[i], 0.f), ws2a, fmaxf(acc1[i], 0.f) * ws2b);
            const float r = red64(t);
            if ((tid & 63) == 63) out[g * 34 + 2 + d0 + i] = r + bias2s;
        }
    }
    if (tid < 128) {
        const int w = tid >> 6, j = tid & 63;
        const float* Wa = (w ? Wn1 : Wc1);
        const float* ba = (w ? bn1 : bc1);
        const float* Wb = (w ? Wn2 : Wc2);
        const float  bb = (w ? bn2 : bc2)[0];
        float h0 = ba[j], h1 = ba[j + 64];
        const float* R0 = Wa + j * DD;
        const float* R1 = Wa + (j + 64) * DD;
#pragma unroll
        for (int k8 = 0; k8 < 16; ++k8) {
            const float4 g0 = *(const float4*)(sU + k8 * 8);
            const float4 g1 = *(const float4*)(sU + k8 * 8 + 4);
            const float4 p00 = *(const float4*)(R0 + k8 * 8), p01 = *(const float4*)(R0 + k8 * 8 + 4);
            const float4 p10 = *(const float4*)(R1 + k8 * 8), p11 = *(const float4*)(R1 + k8 * 8 + 4);
            h0 = fmaf(p00.x, g0.x, h0); h0 = fmaf(p00.y, g0.y, h0);
            h0 = fmaf(p00.z, g0.z, h0); h0 = fmaf(p00.w, g0.w, h0);
            h0 = fmaf(p01.x, g1.x, h0); h0 = fmaf(p01.y, g1.y, h0);
            h0 = fmaf(p01.z, g1.z, h0); h0 = fmaf(p01.w, g1.w, h0);
            h1 = fmaf(p10.x, g0.x, h1); h1 = fmaf(p10.y, g0.y, h1);
            h1 = fmaf(p10.z, g0.z, h1); h1 = fmaf(p10.w, g0.w, h1);
            h1 = fmaf(p11.x, g1.x, h1); h1 = fmaf(p11.y, g1.y, h1);
            h1 = fmaf(p11.z, g1.z, h1); h1 = fmaf(p11.w, g1.w, h1);
        }
        const float t = fmaf(fmaxf(h0, 0.f), Wb[j], fmaxf(h1, 0.f) * Wb[j + 64]);
        const float r = red64(t);
        if (j == 63) out[g * 34 + w] = r + bb;
    }
}

// =============================================================================
extern "C" void kernel_launch(void* const* d_in, const int* in_sizes, int n_in,
                              void* d_out, int out_size, void* d_ws, size_t ws_size,
                              hipStream_t stream)
{
    (void)in_sizes; (void)n_in; (void)out_size;
    const float* x     = (const float*)d_in[0];
    const float* eattr = (const float*)d_in[2];
    const float *W1l = (const float*)d_in[3],  *b1l = (const float*)d_in[4];
    const float *W1r = (const float*)d_in[5],  *b1r = (const float*)d_in[6];
    const float *W1e = (const float*)d_in[7],  *att1 = (const float*)d_in[8],  *bias1 = (const float*)d_in[9];
    const float *W2l = (const float*)d_in[10], *b2l = (const float*)d_in[11];
    const float *W2r = (const float*)d_in[12], *b2r = (const float*)d_in[13];
    const float *W2e = (const float*)d_in[14], *att2 = (const float*)d_in[15], *bias2 = (const float*)d_in[16];
    const float *Wc1 = (const float*)d_in[17], *bc1 = (const float*)d_in[18];
    const float *Wc2 = (const float*)d_in[19], *bc2 = (const float*)d_in[20];
    const float *Ws1 = (const float*)d_in[21], *bs1 = (const float*)d_in[22];
    const float *Ws2 = (const float*)d_in[23], *bs2 = (const float*)d_in[24];
    const float *Wn1 = (const float*)d_in[25], *bn1 = (const float*)d_in[26];
    const float *Wn2 = (const float*)d_in[27], *bn2 = (const float*)d_in[28];
    float* out = (float*)d_out;

    if (d_ws == nullptr || ws_size < WS_NEED) {
        // fallback: proven monolith (142.6 us rocprof)
        planetwars_gnn_mono<<<dim3(NB), dim3(512), 0, stream>>>(
            x, eattr, W1l, b1l, W1r, b1r, W1e, att1, bias1,
            W2l, b2l, W2r, b2r, W2e, att2, bias2,
            Wc1, bc1, Wc2, bc2, Ws1, bs1, Ws2, bs2, Wn1, bn1, Wn2, bn2, out);
        return;
    }

    float* B0 = (float*)d_ws;                 // xl2
    float* B1 = B0 + WS_SLOT;                 // xr2
    float* B2 = B0 + 2 * (long)WS_SLOT;       // h (h1 -> h1n -> h2)

    k_l1   <<<dim3(NB * 2), dim3(512), 0, stream>>>(x, eattr, W1l, b1l, W1r, b1r,
                                                    W1e, att1, bias1, B2);
    k_norm <<<dim3(NB * DD * 4 / 256), dim3(256), 0, stream>>>(B2);
    k_t2   <<<dim3(NB * 2), dim3(512), 0, stream>>>(B2, W2l, b2l, W2r, b2r, B0, B1);
    k_attn <<<dim3(NB * 2), dim3(512), 0, stream>>>(B0, B1, eattr, W2e, att2, bias2, B2, 1);
    k_heads<<<dim3(NB),     dim3(512), 0, stream>>>(B2, Wc1, bc1, Wc2, bc2,
                                                    Ws1, bs1, Ws2, bs2,
                                                    Wn1, bn1, Wn2, bn2, out);
}

// Round 12
// 229.280 us; speedup vs baseline: 1.6268x; 1.3606x over previous
//
#include <hip/hip_runtime.h>

#define PP    32      // nodes per graph
#define FF    16      // input features
#define HH    4       // heads
#define CC    32      // head dim
#define DD    128     // hidden (H*C)
#define EDIM  5
#define EPG   992     // edges per graph = P*(P-1)
#define NB    512     // graphs

// ---- DPP helpers (HW-validated R4) ------------------------------------------
template <int CTRL>
__device__ __forceinline__ float dpp_add(float v) {
    int t = __builtin_amdgcn_update_dpp(0, __builtin_bit_cast(int, v), CTRL, 0xF, 0xF, true);
    return v + __builtin_bit_cast(float, t);
}
template <int CTRL>
__device__ __forceinline__ float dpp_mov(float v) {
    int t = __builtin_amdgcn_update_dpp(0, __builtin_bit_cast(int, v), CTRL, 0xF, 0xF, true);
    return __builtin_bit_cast(float, t);
}
// full 64-lane sum -> result valid in lane 63
__device__ __forceinline__ float red64(float v) {
    v = dpp_add<0x111>(v);   // row_shr:1
    v = dpp_add<0x112>(v);   // row_shr:2
    v = dpp_add<0x114>(v);   // row_shr:4
    v = dpp_add<0x118>(v);   // row_shr:8
    v = dpp_add<0x142>(v);   // row_bcast:15
    v = dpp_add<0x143>(v);   // row_bcast:31
    return v;
}
// quad butterfly sum -> all 4 lanes hold the sum
__device__ __forceinline__ float redquad(float v) {
    v = dpp_add<0xB1>(v);    // quad_perm [1,0,3,2]  (xor 1)
    v = dpp_add<0x4E>(v);    // quad_perm [2,3,0,1]  (xor 2)
    return v;
}
// quad butterfly max -> all 4 lanes hold the max
__device__ __forceinline__ float maxquad(float v) {
    v = fmaxf(v, dpp_mov<0xB1>(v));
    v = fmaxf(v, dpp_mov<0x4E>(v));
    return v;
}

// ---- GATv2 layer (R8-proven: 142.6 us, no spill) ----------------------------
// Score phase lane map: s = tid>>4, h = (tid>>2)&3, c4 = tid&3, ch0=(tid&15)*8.
// Edge attrs STAGED INTO LDS (sE == sOut, dead during score phase) in two
// d-halves (16 KB).  Score loop reads via 16-lane broadcast; xr via 2x
// ds_read_b128.  Diagonal d==s staged from a clamped in-bounds edge and
// discarded by softmax.  sS layout: sS[s*128 + d*4 + h].
__device__ __forceinline__ void attention(const float* __restrict__ eattr,
                                          const float* __restrict__ We, const float* __restrict__ att,
                                          const float* __restrict__ bias,
                                          const float* __restrict__ sMsg, const float* __restrict__ sDst,
                                          float* __restrict__ sS, float* __restrict__ sOut,
                                          int tid, long eBase, bool relu)
{
    float* __restrict__ sE = sOut;                    // staging alias (dead until aggregation)
    {
        const int s  = tid >> 4;
        const int ch0 = (tid & 15) * 8;               // h*32 + c4*8
        // preload We[ch0..ch0+7][0..4] (40 consecutive floats), att, xl
        float we[40], at[8], xl[8];
#pragma unroll
        for (int q = 0; q < 10; ++q)
            *(float4*)(we + q * 4) = *(const float4*)(We + ch0 * EDIM + q * 4);
        *(float4*)(at)     = *(const float4*)(att + ch0);
        *(float4*)(at + 4) = *(const float4*)(att + ch0 + 4);
        *(float4*)(xl)     = *(const float4*)(sMsg + s * DD + ch0);
        *(float4*)(xl + 4) = *(const float4*)(sMsg + s * DD + ch0 + 4);

        for (int halfd = 0; halfd < 2; ++halfd) {
            const int d0 = halfd * 16;
            // ---- stage edges (s, d0 + dl): one edge per thread (32s x 16d)
            {
                const int dl = tid & 15;
                const int d = d0 + dl;
                int jj = d - (d > s);
                if (jj > 30) jj = 30;                 // d==s==31 clamp (discarded)
                const float* ea = eattr + (eBase + s * 31 + jj) * EDIM;
                const float e0 = ea[0], e1 = ea[1], e2 = ea[2], e3 = ea[3], e4 = ea[4];
                float* p = sE + (((s << 4) | dl) << 3);
                *(float4*)p = make_float4(e0, e1, e2, e3);
                p[4] = e4;
            }
            __syncthreads();
            // ---- score loop over this d-half: LDS reads only
#pragma unroll 2
            for (int dl = 0; dl < 16; ++dl) {
                const int d = d0 + dl;
                const float* ep = sE + (((s << 4) | dl) << 3);
                const float4 ef = *(const float4*)ep;
                const float e4v = ep[4];
                float xr[8];
                *(float4*)(xr)     = *(const float4*)(sDst + d * DD + ch0);
                *(float4*)(xr + 4) = *(const float4*)(sDst + d * DD + ch0 + 4);
                float acc0 = 0.f, acc1 = 0.f;
#pragma unroll
                for (int c = 0; c < 8; ++c) {
                    float v = xl[c] + xr[c];
                    const float* w = we + c * EDIM;
                    v = fmaf(w[0], ef.x, v); v = fmaf(w[1], ef.y, v); v = fmaf(w[2], ef.z, v);
                    v = fmaf(w[3], ef.w, v); v = fmaf(w[4], e4v, v);
                    v = fmaf(0.4f, fabsf(v), 0.6f * v);   // leaky_relu(., 0.2)
                    if (c & 1) acc1 = fmaf(v, at[c], acc1);
                    else       acc0 = fmaf(v, at[c], acc0);
                }
                const float r = redquad(acc0 + acc1);     // sum over 4 c4-chunks
                if ((tid & 3) == 0)
                    sS[s * DD + d * HH + ((tid >> 2) & 3)] = r;
            }
            __syncthreads();                              // sE half consumed
        }
    }
    // ---- segment softmax over s != d per column (d*4+h): all 512 threads,
    // quad per column, r = tid&3 owns 8 rows, DPP quad reduce.
    {
        const int col = tid >> 2;
        const int r   = tid & 3;
        const int dd  = col >> 2;                     // destination node of this column
        float v[8];
        float mx = -3.4e38f;
#pragma unroll
        for (int i = 0; i < 8; ++i) {
            const int s = r * 8 + i;
            v[i] = sS[s * DD + col];
            mx = (s == dd) ? mx : fmaxf(mx, v[i]);
        }
        mx = maxquad(mx);
        float sum = 0.f;
#pragma unroll
        for (int i = 0; i < 8; ++i) {
            const int s = r * 8 + i;
            float ex = __expf(v[i] - mx);
            ex = (s == dd) ? 0.f : ex;                // diagonal forced to 0
            v[i] = ex; sum += ex;
        }
        sum = redquad(sum);
        const float inv = 1.f / (sum + 1e-16f);
#pragma unroll
        for (int i = 0; i < 8; ++i)
            sS[(r * 8 + i) * DD + col] = v[i] * inv;
    }
    __syncthreads();
    // ---- aggregation: out[d][ch] = bias[ch] + sum_s alpha[s][d,h(ch)] * msg[s][ch]
    {
        const int d = tid >> 4, sub = tid & 15;
#pragma unroll
        for (int half = 0; half < 2; ++half) {
            const int ch4 = half * 16 + sub;
            const int idx = d * HH + (ch4 >> 3);
            const float* bp = bias + ch4 * 4;
            float4 acc = make_float4(bp[0], bp[1], bp[2], bp[3]);
#pragma unroll
            for (int s = 0; s < PP; ++s) {
                const float a = sS[s * DD + idx];     // alpha(d==s) == 0
                const float4 xv = *(const float4*)(sMsg + s * DD + ch4 * 4);
                acc.x = fmaf(a, xv.x, acc.x);
                acc.y = fmaf(a, xv.y, acc.y);
                acc.z = fmaf(a, xv.z, acc.z);
                acc.w = fmaf(a, xv.w, acc.w);
            }
            if (relu) {
                acc.x = fmaxf(acc.x, 0.f); acc.y = fmaxf(acc.y, 0.f);
                acc.z = fmaxf(acc.z, 0.f); acc.w = fmaxf(acc.w, 0.f);
            }
            *(float4*)(sOut + d * DD + ch4 * 4) = acc;
        }
    }
}

extern "C" __global__ void __launch_bounds__(512)
__attribute__((amdgpu_waves_per_eu(4, 4)))
planetwars_gnn_kernel(const float* __restrict__ x, const float* __restrict__ eattr,
                      const float* __restrict__ W1l, const float* __restrict__ b1l,
                      const float* __restrict__ W1r, const float* __restrict__ b1r,
                      const float* __restrict__ W1e, const float* __restrict__ att1, const float* __restrict__ bias1,
                      const float* __restrict__ W2l, const float* __restrict__ b2l,
                      const float* __restrict__ W2r, const float* __restrict__ b2r,
                      const float* __restrict__ W2e, const float* __restrict__ att2, const float* __restrict__ bias2,
                      const float* __restrict__ Wc1, const float* __restrict__ bc1,
                      const float* __restrict__ Wc2, const float* __restrict__ bc2,
                      const float* __restrict__ Ws1, const float* __restrict__ bs1,
                      const float* __restrict__ Ws2, const float* __restrict__ bs2,
                      const float* __restrict__ Wn1, const float* __restrict__ bn1,
                      const float* __restrict__ Wn2, const float* __restrict__ bn2,
                      float* __restrict__ out)
{
    __shared__ __align__(16) float sA[PP * DD];   // xl1 -> xl2
    __shared__ __align__(16) float sB[PP * DD];   // xr1 -> xr2
    __shared__ __align__(16) float sH[PP * DD];   // edge staging | h1 -> h2
    __shared__ __align__(16) float sU[PP * DD];   // x | scores/alpha | g

    const int tid = threadIdx.x;
    const int g = blockIdx.x;
    const long eBase = (long)g * EPG;

    // ---- load x tile (32x16), one element per thread
    sU[tid] = x[g * PP * FF + tid];
    __syncthreads();

    // ---- layer-1 node transforms (K = 16): xl1 -> sA, xr1 -> sB
    {
        const int j = tid & 127, d0 = (tid >> 7) * 8;
        float wl[16], wr[16];
#pragma unroll
        for (int q = 0; q < 4; ++q) {
            *(float4*)(wl + q * 4) = *(const float4*)(W1l + j * FF + q * 4);
            *(float4*)(wr + q * 4) = *(const float4*)(W1r + j * FF + q * 4);
        }
        const float bl = b1l[j], br = b1r[j];
#pragma unroll
        for (int i = 0; i < 8; ++i) {
            const float* xr = sU + (d0 + i) * FF;
            float al = bl, ar = br;
#pragma unroll
            for (int k = 0; k < FF; ++k) {
                const float xv = xr[k];
                al = fmaf(wl[k], xv, al);
                ar = fmaf(wr[k], xv, ar);
            }
            sA[(d0 + i) * DD + j] = al;
            sB[(d0 + i) * DD + j] = ar;
        }
    }
    __syncthreads();

    attention(eattr, W1e, att1, bias1, sA, sB, sU, sH, tid, eBase, false);
    __syncthreads();

    // ---- MeanSubtractionNorm per graph, then ReLU (512 threads, quad/column)
    {
        const int col = tid >> 2, r = tid & 3;
        float v[8];
        float ssum = 0.f;
#pragma unroll
        for (int i = 0; i < 8; ++i) {
            v[i] = sH[(r * 8 + i) * DD + col];
            ssum += v[i];
        }
        ssum = redquad(ssum);
        const float mn = ssum * (1.0f / 32.0f);
#pragma unroll
        for (int i = 0; i < 8; ++i)
            sH[(r * 8 + i) * DD + col] = fmaxf(v[i] - mn, 0.f);
    }
    __syncthreads();

    // ---- fused layer-2 node transforms (K = 128), register-weight scheme.
    // R11's isolated k_t2 showed this phase is L1-request-throughput bound:
    // per-lane weight-row loads hit 64 distinct 512B-strided lines per instr.
    // New thread map: j = tid&127, m = (tid>>7)&1 (L/R), half = tid>>8
    // (wave-uniform).  Weight row streams through regs in 4 K-chunks ->
    // 32 scattered float4/thread instead of 128, redundancy 4x -> 2x.
    // h reads are wave-uniform LDS broadcasts.  Per-output k-order (ascending,
    // fmaf chain from bias) identical to R8 -> bit-identical results.
    {
        const int j    = tid & 127;
        const int m    = (tid >> 7) & 1;
        const int half = tid >> 8;                    // wave-uniform
        const float* Wrow = (m ? W2r : W2l) + j * DD;
        const float  bini = m ? b2r[j] : b2l[j];
        float acc[16];
#pragma unroll
        for (int i = 0; i < 16; ++i) acc[i] = bini;
        for (int kc = 0; kc < 4; ++kc) {
            float w[32];
#pragma unroll
            for (int q = 0; q < 8; ++q)
                *(float4*)(w + q * 4) = *(const float4*)(Wrow + kc * 32 + q * 4);
#pragma unroll
            for (int k4 = 0; k4 < 8; ++k4) {
#pragma unroll
                for (int i = 0; i < 16; ++i) {
                    const float4 hv = *(const float4*)(sH + (half * 16 + i) * DD + kc * 32 + k4 * 4);
                    acc[i] = fmaf(w[k4 * 4 + 0], hv.x, acc[i]);
                    acc[i] = fmaf(w[k4 * 4 + 1], hv.y, acc[i]);
                    acc[i] = fmaf(w[k4 * 4 + 2], hv.z, acc[i]);
                    acc[i] = fmaf(w[k4 * 4 + 3], hv.w, acc[i]);
                }
            }
        }
        float* dst = m ? sB : sA;
#pragma unroll
        for (int i = 0; i < 16; ++i)
            dst[(half * 16 + i) * DD + j] = acc[i];
    }
    __syncthreads();

    attention(eattr, W2e, att2, bias2, sA, sB, sU, sH, tid, eBase, true);
    __syncthreads();

    // ---- global mean pool -> sU[0..127] (512 threads, quad per column)
    {
        const int col = tid >> 2, r = tid & 3;
        float ssum = 0.f;
#pragma unroll
        for (int i = 0; i < 8; ++i) ssum += sH[(r * 8 + i) * DD + col];
        ssum = redquad(ssum);
        if (r == 0) sU[col] = ssum * (1.0f / 32.0f);
    }
    __syncthreads();

    // ---- source-actor: fused Ws1-GEMM + Ws2 dot -> logits written directly.
    {
        const int jj = tid & 63, d0 = (tid >> 6) * 4;
        const float b0 = bs1[jj], b1 = bs1[jj + 64];
        float acc0[4], acc1[4];
#pragma unroll
        for (int i = 0; i < 4; ++i) { acc0[i] = b0; acc1[i] = b1; }
        const float* W0 = Ws1 + jj * DD;
        const float* W1 = Ws1 + (jj + 64) * DD;
        for (int k8 = 0; k8 < 16; ++k8) {
            const float4 w00 = *(const float4*)(W0 + k8 * 8), w01 = *(const float4*)(W0 + k8 * 8 + 4);
            const float4 w10 = *(const float4*)(W1 + k8 * 8), w11 = *(const float4*)(W1 + k8 * 8 + 4);
#pragma unroll
            for (int i = 0; i < 4; ++i) {
                const float4 a0 = *(const float4*)(sH + (d0 + i) * DD + k8 * 8);
                const float4 a1 = *(const float4*)(sH + (d0 + i) * DD + k8 * 8 + 4);
                acc0[i] = fmaf(w00.x, a0.x, acc0[i]); acc0[i] = fmaf(w00.y, a0.y, acc0[i]);
                acc0[i] = fmaf(w00.z, a0.z, acc0[i]); acc0[i] = fmaf(w00.w, a0.w, acc0[i]);
                acc0[i] = fmaf(w01.x, a1.x, acc0[i]); acc0[i] = fmaf(w01.y, a1.y, acc0[i]);
                acc0[i] = fmaf(w01.z, a1.z, acc0[i]); acc0[i] = fmaf(w01.w, a1.w, acc0[i]);
                acc1[i] = fmaf(w10.x, a0.x, acc1[i]); acc1[i] = fmaf(w10.y, a0.y, acc1[i]);
                acc1[i] = fmaf(w10.z, a0.z, acc1[i]); acc1[i] = fmaf(w10.w, a0.w, acc1[i]);
                acc1[i] = fmaf(w11.x, a1.x, acc1[i]); acc1[i] = fmaf(w11.y, a1.y, acc1[i]);
                acc1[i] = fmaf(w11.z, a1.z, acc1[i]); acc1[i] = fmaf(w11.w, a1.w, acc1[i]);
            }
        }
        const float ws2a = Ws2[jj], ws2b = Ws2[jj + 64];
        const float bias2s = bs2[0];
#pragma unroll
        for (int i = 0; i < 4; ++i) {
            const float t = fmaf(fmaxf(acc0[i], 0.f), ws2a, fmaxf(acc1[i], 0.f) * ws2b);
            const float r = red64(t);                 // lane 63 holds node logit
            if ((tid & 63) == 63) out[g * 34 + 2 + d0 + i] = r + bias2s;
        }
    }

    // ---- value / noop: wave 0 = critic, wave 1 = noop (fused hidden + dot)
    if (tid < 128) {
        const int w = tid >> 6, j = tid & 63;
        const float* Wa = (w ? Wn1 : Wc1);
        const float* ba = (w ? bn1 : bc1);
        const float* Wb = (w ? Wn2 : Wc2);
        const float  bb = (w ? bn2 : bc2)[0];
        float h0 = ba[j], h1 = ba[j + 64];
        const float* R0 = Wa + j * DD;
        const float* R1 = Wa + (j + 64) * DD;
#pragma unroll
        for (int k8 = 0; k8 < 16; ++k8) {
            const float4 g0 = *(const float4*)(sU + k8 * 8);
            const float4 g1 = *(const float4*)(sU + k8 * 8 + 4);
            const float4 p00 = *(const float4*)(R0 + k8 * 8), p01 = *(const float4*)(R0 + k8 * 8 + 4);
            const float4 p10 = *(const float4*)(R1 + k8 * 8), p11 = *(const float4*)(R1 + k8 * 8 + 4);
            h0 = fmaf(p00.x, g0.x, h0); h0 = fmaf(p00.y, g0.y, h0);
            h0 = fmaf(p00.z, g0.z, h0); h0 = fmaf(p00.w, g0.w, h0);
            h0 = fmaf(p01.x, g1.x, h0); h0 = fmaf(p01.y, g1.y, h0);
            h0 = fmaf(p01.z, g1.z, h0); h0 = fmaf(p01.w, g1.w, h0);
            h1 = fmaf(p10.x, g0.x, h1); h1 = fmaf(p10.y, g0.y, h1);
            h1 = fmaf(p10.z, g0.z, h1); h1 = fmaf(p10.w, g0.w, h1);
            h1 = fmaf(p11.x, g1.x, h1); h1 = fmaf(p11.y, g1.y, h1);
            h1 = fmaf(p11.z, g1.z, h1); h1 = fmaf(p11.w, g1.w, h1);
        }
        const float t = fmaf(fmaxf(h0, 0.f), Wb[j], fmaxf(h1, 0.f) * Wb[j + 64]);
        const float r = red64(t);
        if (j == 63) out[g * 34 + w] = r + bb;
    }
}

extern "C" void kernel_launch(void* const* d_in, const int* in_sizes, int n_in,
                              void* d_out, int out_size, void* d_ws, size_t ws_size,
                              hipStream_t stream)
{
    (void)in_sizes; (void)n_in; (void)d_ws; (void)ws_size; (void)out_size;
    // d_in[1] (edge_index) unused: edge structure is analytic (validated R3).
    planetwars_gnn_kernel<<<dim3(NB), dim3(512), 0, stream>>>(
        (const float*)d_in[0], (const float*)d_in[2],
        (const float*)d_in[3], (const float*)d_in[4], (const float*)d_in[5], (const float*)d_in[6],
        (const float*)d_in[7], (const float*)d_in[8], (const float*)d_in[9],
        (const float*)d_in[10], (const float*)d_in[11], (const float*)d_in[12], (const float*)d_in[13],
        (const float*)d_in[14], (const float*)d_in[15], (const float*)d_in[16],
        (const float*)d_in[17], (const float*)d_in[18], (const float*)d_in[19], (const float*)d_in[20],
        (const float*)d_in[21], (const float*)d_in[22], (const float*)d_in[23], (const float*)d_in[24],
        (const float*)d_in[25], (const float*)d_in[26], (const float*)d_in[27], (const float*)d_in[28],
        (float*)d_out);
}

// Round 13
// 226.185 us; speedup vs baseline: 1.6491x; 1.0137x over previous
//
#include <hip/hip_runtime.h>

#define PP    32      // nodes per graph
#define FF    16      // input features
#define HH    4       // heads
#define CC    32      // head dim
#define DD    128     // hidden (H*C)
#define EDIM  5
#define EPG   992     // edges per graph = P*(P-1)
#define NB    512     // graphs

// ---- DPP helpers (HW-validated R4) ------------------------------------------
template <int CTRL>
__device__ __forceinline__ float dpp_add(float v) {
    int t = __builtin_amdgcn_update_dpp(0, __builtin_bit_cast(int, v), CTRL, 0xF, 0xF, true);
    return v + __builtin_bit_cast(float, t);
}
template <int CTRL>
__device__ __forceinline__ float dpp_mov(float v) {
    int t = __builtin_amdgcn_update_dpp(0, __builtin_bit_cast(int, v), CTRL, 0xF, 0xF, true);
    return __builtin_bit_cast(float, t);
}
// full 64-lane sum -> result valid in lane 63
__device__ __forceinline__ float red64(float v) {
    v = dpp_add<0x111>(v);   // row_shr:1
    v = dpp_add<0x112>(v);   // row_shr:2
    v = dpp_add<0x114>(v);   // row_shr:4
    v = dpp_add<0x118>(v);   // row_shr:8
    v = dpp_add<0x142>(v);   // row_bcast:15
    v = dpp_add<0x143>(v);   // row_bcast:31
    return v;
}
// quad butterfly sum -> all 4 lanes hold the sum
__device__ __forceinline__ float redquad(float v) {
    v = dpp_add<0xB1>(v);    // quad_perm [1,0,3,2]  (xor 1)
    v = dpp_add<0x4E>(v);    // quad_perm [2,3,0,1]  (xor 2)
    return v;
}
// quad butterfly max -> all 4 lanes hold the max
__device__ __forceinline__ float maxquad(float v) {
    v = fmaxf(v, dpp_mov<0xB1>(v));
    v = fmaxf(v, dpp_mov<0x4E>(v));
    return v;
}

// ---- GATv2 layer (R8-proven structure) --------------------------------------
// Score phase lane map: s = tid>>4, h = (tid>>2)&3, c4 = tid&3, ch0=(tid&15)*8.
// Edge attrs STAGED INTO LDS (sE == sOut, dead during score phase) in two
// d-halves (16 KB).  Score loop reads via 16-lane broadcast; xr via 2x
// ds_read_b128.  Diagonal d==s staged from a clamped in-bounds edge and
// discarded by softmax.  sS layout: sS[s*128 + d*4 + h].
__device__ __forceinline__ void attention(const float* __restrict__ eattr,
                                          const float* __restrict__ We, const float* __restrict__ att,
                                          const float* __restrict__ bias,
                                          const float* __restrict__ sMsg, const float* __restrict__ sDst,
                                          float* __restrict__ sS, float* __restrict__ sOut,
                                          int tid, long eBase, bool relu)
{
    float* __restrict__ sE = sOut;                    // staging alias (dead until aggregation)
    {
        const int s  = tid >> 4;
        const int ch0 = (tid & 15) * 8;               // h*32 + c4*8
        // preload We[ch0..ch0+7][0..4] (40 consecutive floats), att, xl
        float we[40], at[8], xl[8];
#pragma unroll
        for (int q = 0; q < 10; ++q)
            *(float4*)(we + q * 4) = *(const float4*)(We + ch0 * EDIM + q * 4);
        *(float4*)(at)     = *(const float4*)(att + ch0);
        *(float4*)(at + 4) = *(const float4*)(att + ch0 + 4);
        *(float4*)(xl)     = *(const float4*)(sMsg + s * DD + ch0);
        *(float4*)(xl + 4) = *(const float4*)(sMsg + s * DD + ch0 + 4);

        for (int halfd = 0; halfd < 2; ++halfd) {
            const int d0 = halfd * 16;
            // ---- stage edges (s, d0 + dl): one edge per thread (32s x 16d)
            {
                const int dl = tid & 15;
                const int d = d0 + dl;
                int jj = d - (d > s);
                if (jj > 30) jj = 30;                 // d==s==31 clamp (discarded)
                const float* ea = eattr + (eBase + s * 31 + jj) * EDIM;
                const float e0 = ea[0], e1 = ea[1], e2 = ea[2], e3 = ea[3], e4 = ea[4];
                float* p = sE + (((s << 4) | dl) << 3);
                *(float4*)p = make_float4(e0, e1, e2, e3);
                p[4] = e4;
            }
            __syncthreads();
            // ---- score loop over this d-half: LDS reads only
#pragma unroll 2
            for (int dl = 0; dl < 16; ++dl) {
                const int d = d0 + dl;
                const float* ep = sE + (((s << 4) | dl) << 3);
                const float4 ef = *(const float4*)ep;
                const float e4v = ep[4];
                float xr[8];
                *(float4*)(xr)     = *(const float4*)(sDst + d * DD + ch0);
                *(float4*)(xr + 4) = *(const float4*)(sDst + d * DD + ch0 + 4);
                float acc0 = 0.f, acc1 = 0.f;
#pragma unroll
                for (int c = 0; c < 8; ++c) {
                    float v = xl[c] + xr[c];
                    const float* w = we + c * EDIM;
                    v = fmaf(w[0], ef.x, v); v = fmaf(w[1], ef.y, v); v = fmaf(w[2], ef.z, v);
                    v = fmaf(w[3], ef.w, v); v = fmaf(w[4], e4v, v);
                    v = fmaf(0.4f, fabsf(v), 0.6f * v);   // leaky_relu(., 0.2)
                    if (c & 1) acc1 = fmaf(v, at[c], acc1);
                    else       acc0 = fmaf(v, at[c], acc0);
                }
                const float r = redquad(acc0 + acc1);     // sum over 4 c4-chunks
                if ((tid & 3) == 0)
                    sS[s * DD + d * HH + ((tid >> 2) & 3)] = r;
            }
            __syncthreads();                              // sE half consumed
        }
    }
    // ---- segment softmax over s != d per column (d*4+h): all 512 threads,
    // quad per column, r = tid&3 owns 8 rows, DPP quad reduce.
    {
        const int col = tid >> 2;
        const int r   = tid & 3;
        const int dd  = col >> 2;                     // destination node of this column
        float v[8];
        float mx = -3.4e38f;
#pragma unroll
        for (int i = 0; i < 8; ++i) {
            const int s = r * 8 + i;
            v[i] = sS[s * DD + col];
            mx = (s == dd) ? mx : fmaxf(mx, v[i]);
        }
        mx = maxquad(mx);
        float sum = 0.f;
#pragma unroll
        for (int i = 0; i < 8; ++i) {
            const int s = r * 8 + i;
            float ex = __expf(v[i] - mx);
            ex = (s == dd) ? 0.f : ex;                // diagonal forced to 0
            v[i] = ex; sum += ex;
        }
        sum = redquad(sum);
        const float inv = 1.f / (sum + 1e-16f);
#pragma unroll
        for (int i = 0; i < 8; ++i)
            sS[(r * 8 + i) * DD + col] = v[i] * inv;
    }
    __syncthreads();
    // ---- aggregation: out[d][ch] = bias[ch] + sum_s alpha[s][d,h(ch)] * msg[s][ch]
    {
        const int d = tid >> 4, sub = tid & 15;
#pragma unroll
        for (int half = 0; half < 2; ++half) {
            const int ch4 = half * 16 + sub;
            const int idx = d * HH + (ch4 >> 3);
            const float* bp = bias + ch4 * 4;
            float4 acc = make_float4(bp[0], bp[1], bp[2], bp[3]);
#pragma unroll
            for (int s = 0; s < PP; ++s) {
                const float a = sS[s * DD + idx];     // alpha(d==s) == 0
                const float4 xv = *(const float4*)(sMsg + s * DD + ch4 * 4);
                acc.x = fmaf(a, xv.x, acc.x);
                acc.y = fmaf(a, xv.y, acc.y);
                acc.z = fmaf(a, xv.z, acc.z);
                acc.w = fmaf(a, xv.w, acc.w);
            }
            if (relu) {
                acc.x = fmaxf(acc.x, 0.f); acc.y = fmaxf(acc.y, 0.f);
                acc.z = fmaxf(acc.z, 0.f); acc.w = fmaxf(acc.w, 0.f);
            }
            *(float4*)(sOut + d * DD + ch4 * 4) = acc;
        }
    }
}

extern "C" __global__ void __launch_bounds__(512)
__attribute__((amdgpu_waves_per_eu(4, 4)))
planetwars_gnn_kernel(const float* __restrict__ x, const float* __restrict__ eattr,
                      const float* __restrict__ W1l, const float* __restrict__ b1l,
                      const float* __restrict__ W1r, const float* __restrict__ b1r,
                      const float* __restrict__ W1e, const float* __restrict__ att1, const float* __restrict__ bias1,
                      const float* __restrict__ W2l, const float* __restrict__ b2l,
                      const float* __restrict__ W2r, const float* __restrict__ b2r,
                      const float* __restrict__ W2e, const float* __restrict__ att2, const float* __restrict__ bias2,
                      const float* __restrict__ Wc1, const float* __restrict__ bc1,
                      const float* __restrict__ Wc2, const float* __restrict__ bc2,
                      const float* __restrict__ Ws1, const float* __restrict__ bs1,
                      const float* __restrict__ Ws2, const float* __restrict__ bs2,
                      const float* __restrict__ Wn1, const float* __restrict__ bn1,
                      const float* __restrict__ Wn2, const float* __restrict__ bn2,
                      float* __restrict__ out)
{
    __shared__ __align__(16) float sA[PP * DD];   // xl1 -> xl2
    __shared__ __align__(16) float sB[PP * DD];   // xr1 -> xr2
    __shared__ __align__(16) float sH[PP * DD];   // edge staging | h1 -> h2
    __shared__ __align__(16) float sU[PP * DD];   // x | scores/alpha | g

    const int tid = threadIdx.x;
    const int g = blockIdx.x;
    const long eBase = (long)g * EPG;

    // ---- load x tile (32x16), one element per thread
    sU[tid] = x[g * PP * FF + tid];
    __syncthreads();

    // ---- layer-1 node transforms (K = 16): xl1 -> sA, xr1 -> sB
    {
        const int j = tid & 127, d0 = (tid >> 7) * 8;
        float wl[16], wr[16];
#pragma unroll
        for (int q = 0; q < 4; ++q) {
            *(float4*)(wl + q * 4) = *(const float4*)(W1l + j * FF + q * 4);
            *(float4*)(wr + q * 4) = *(const float4*)(W1r + j * FF + q * 4);
        }
        const float bl = b1l[j], br = b1r[j];
#pragma unroll
        for (int i = 0; i < 8; ++i) {
            const float* xr = sU + (d0 + i) * FF;
            float al = bl, ar = br;
#pragma unroll
            for (int k = 0; k < FF; ++k) {
                const float xv = xr[k];
                al = fmaf(wl[k], xv, al);
                ar = fmaf(wr[k], xv, ar);
            }
            sA[(d0 + i) * DD + j] = al;
            sB[(d0 + i) * DD + j] = ar;
        }
    }
    __syncthreads();

    attention(eattr, W1e, att1, bias1, sA, sB, sU, sH, tid, eBase, false);
    __syncthreads();

    // ---- MeanSubtractionNorm per graph, then ReLU (512 threads, quad/column)
    {
        const int col = tid >> 2, r = tid & 3;
        float v[8];
        float ssum = 0.f;
#pragma unroll
        for (int i = 0; i < 8; ++i) {
            v[i] = sH[(r * 8 + i) * DD + col];
            ssum += v[i];
        }
        ssum = redquad(ssum);
        const float mn = ssum * (1.0f / 32.0f);
#pragma unroll
        for (int i = 0; i < 8; ++i)
            sH[(r * 8 + i) * DD + col] = fmaxf(v[i] - mn, 0.f);
    }
    __syncthreads();

    // ---- fused layer-2 node transforms (K = 128), register-weight scheme.
    // R12 proved the scheme (-13%: L1-scatter was the stall) but spilled
    // (WRITE 34 MB: acc[16]+w[32] ~ 70 live regs > 64).  R13: weights stream
    // in 8 chunks of 16 floats -> acc[16]+w[16]+temps ~ 50 regs, no spill.
    // Scattered-load count unchanged (32 float4/thread); per-output k-order
    // still ascending 0..127, same fmaf chain -> bit-identical results.
    // Thread map: j = tid&127, m = (tid>>7)&1 (L/R), half = tid>>8 (wave-
    // uniform); h reads are wave-uniform LDS broadcasts.
    {
        const int j    = tid & 127;
        const int m    = (tid >> 7) & 1;
        const int half = tid >> 8;                    // wave-uniform
        const float* Wrow = (m ? W2r : W2l) + j * DD;
        const float  bini = m ? b2r[j] : b2l[j];
        float acc[16];
#pragma unroll
        for (int i = 0; i < 16; ++i) acc[i] = bini;
        for (int kc = 0; kc < 8; ++kc) {
            float w[16];
#pragma unroll
            for (int q = 0; q < 4; ++q)
                *(float4*)(w + q * 4) = *(const float4*)(Wrow + kc * 16 + q * 4);
#pragma unroll
            for (int k4 = 0; k4 < 4; ++k4) {
#pragma unroll
                for (int i = 0; i < 16; ++i) {
                    const float4 hv = *(const float4*)(sH + (half * 16 + i) * DD + kc * 16 + k4 * 4);
                    acc[i] = fmaf(w[k4 * 4 + 0], hv.x, acc[i]);
                    acc[i] = fmaf(w[k4 * 4 + 1], hv.y, acc[i]);
                    acc[i] = fmaf(w[k4 * 4 + 2], hv.z, acc[i]);
                    acc[i] = fmaf(w[k4 * 4 + 3], hv.w, acc[i]);
                }
            }
        }
        float* dst = m ? sB : sA;
#pragma unroll
        for (int i = 0; i < 16; ++i)
            dst[(half * 16 + i) * DD + j] = acc[i];
    }
    __syncthreads();

    attention(eattr, W2e, att2, bias2, sA, sB, sU, sH, tid, eBase, true);
    __syncthreads();

    // ---- global mean pool -> sU[0..127] (512 threads, quad per column)
    {
        const int col = tid >> 2, r = tid & 3;
        float ssum = 0.f;
#pragma unroll
        for (int i = 0; i < 8; ++i) ssum += sH[(r * 8 + i) * DD + col];
        ssum = redquad(ssum);
        if (r == 0) sU[col] = ssum * (1.0f / 32.0f);
    }
    __syncthreads();

    // ---- source-actor: fused Ws1-GEMM + Ws2 dot -> logits written directly.
    {
        const int jj = tid & 63, d0 = (tid >> 6) * 4;
        const float b0 = bs1[jj], b1 = bs1[jj + 64];
        float acc0[4], acc1[4];
#pragma unroll
        for (int i = 0; i < 4; ++i) { acc0[i] = b0; acc1[i] = b1; }
        const float* W0 = Ws1 + jj * DD;
        const float* W1 = Ws1 + (jj + 64) * DD;
        for (int k8 = 0; k8 < 16; ++k8) {
            const float4 w00 = *(const float4*)(W0 + k8 * 8), w01 = *(const float4*)(W0 + k8 * 8 + 4);
            const float4 w10 = *(const float4*)(W1 + k8 * 8), w11 = *(const float4*)(W1 + k8 * 8 + 4);
#pragma unroll
            for (int i = 0; i < 4; ++i) {
                const float4 a0 = *(const float4*)(sH + (d0 + i) * DD + k8 * 8);
                const float4 a1 = *(const float4*)(sH + (d0 + i) * DD + k8 * 8 + 4);
                acc0[i] = fmaf(w00.x, a0.x, acc0[i]); acc0[i] = fmaf(w00.y, a0.y, acc0[i]);
                acc0[i] = fmaf(w00.z, a0.z, acc0[i]); acc0[i] = fmaf(w00.w, a0.w, acc0[i]);
                acc0[i] = fmaf(w01.x, a1.x, acc0[i]); acc0[i] = fmaf(w01.y, a1.y, acc0[i]);
                acc0[i] = fmaf(w01.z, a1.z, acc0[i]); acc0[i] = fmaf(w01.w, a1.w, acc0[i]);
                acc1[i] = fmaf(w10.x, a0.x, acc1[i]); acc1[i] = fmaf(w10.y, a0.y, acc1[i]);
                acc1[i] = fmaf(w10.z, a0.z, acc1[i]); acc1[i] = fmaf(w10.w, a0.w, acc1[i]);
                acc1[i] = fmaf(w11.x, a1.x, acc1[i]); acc1[i] = fmaf(w11.y, a1.y, acc1[i]);
                acc1[i] = fmaf(w11.z, a1.z, acc1[i]); acc1[i] = fmaf(w11.w, a1.w, acc1[i]);
            }
        }
        const float ws2a = Ws2[jj], ws2b = Ws2[jj + 64];
        const float bias2s = bs2[0];
#pragma unroll
        for (int i = 0; i < 4; ++i) {
            const float t = fmaf(fmaxf(acc0[i], 0.f), ws2a, fmaxf(acc1[i], 0.f) * ws2b);
            const float r = red64(t);                 // lane 63 holds node logit
            if ((tid & 63) == 63) out[g * 34 + 2 + d0 + i] = r + bias2s;
        }
    }

    // ---- value / noop: wave 0 = critic, wave 1 = noop (fused hidden + dot)
    if (tid < 128) {
        const int w = tid >> 6, j = tid & 63;
        const float* Wa = (w ? Wn1 : Wc1);
        const float* ba = (w ? bn1 : bc1);
        const float* Wb = (w ? Wn2 : Wc2);
        const float  bb = (w ? bn2 : bc2)[0];
        float h0 = ba[j], h1 = ba[j + 64];
        const float* R0 = Wa + j * DD;
        const float* R1 = Wa + (j + 64) * DD;
#pragma unroll
        for (int k8 = 0; k8 < 16; ++k8) {
            const float4 g0 = *(const float4*)(sU + k8 * 8);
            const float4 g1 = *(const float4*)(sU + k8 * 8 + 4);
            const float4 p00 = *(const float4*)(R0 + k8 * 8), p01 = *(const float4*)(R0 + k8 * 8 + 4);
            const float4 p10 = *(const float4*)(R1 + k8 * 8), p11 = *(const float4*)(R1 + k8 * 8 + 4);
            h0 = fmaf(p00.x, g0.x, h0); h0 = fmaf(p00.y, g0.y, h0);
            h0 = fmaf(p00.z, g0.z, h0); h0 = fmaf(p00.w, g0.w, h0);
            h0 = fmaf(p01.x, g1.x, h0); h0 = fmaf(p01.y, g1.y, h0);
            h0 = fmaf(p01.z, g1.z, h0); h0 = fmaf(p01.w, g1.w, h0);
            h1 = fmaf(p10.x, g0.x, h1); h1 = fmaf(p10.y, g0.y, h1);
            h1 = fmaf(p10.z, g0.z, h1); h1 = fmaf(p10.w, g0.w, h1);
            h1 = fmaf(p11.x, g1.x, h1); h1 = fmaf(p11.y, g1.y, h1);
            h1 = fmaf(p11.z, g1.z, h1); h1 = fmaf(p11.w, g1.w, h1);
        }
        const float t = fmaf(fmaxf(h0, 0.f), Wb[j], fmaxf(h1, 0.f) * Wb[j + 64]);
        const float r = red64(t);
        if (j == 63) out[g * 34 + w] = r + bb;
    }
}

extern "C" void kernel_launch(void* const* d_in, const int* in_sizes, int n_in,
                              void* d_out, int out_size, void* d_ws, size_t ws_size,
                              hipStream_t stream)
{
    (void)in_sizes; (void)n_in; (void)d_ws; (void)ws_size; (void)out_size;
    // d_in[1] (edge_index) unused: edge structure is analytic (validated R3).
    planetwars_gnn_kernel<<<dim3(NB), dim3(512), 0, stream>>>(
        (const float*)d_in[0], (const float*)d_in[2],
        (const float*)d_in[3], (const float*)d_in[4], (const float*)d_in[5], (const float*)d_in[6],
        (const float*)d_in[7], (const float*)d_in[8], (const float*)d_in[9],
        (const float*)d_in[10], (const float*)d_in[11], (const float*)d_in[12], (const float*)d_in[13],
        (const float*)d_in[14], (const float*)d_in[15], (const float*)d_in[16],
        (const float*)d_in[17], (const float*)d_in[18], (const float*)d_in[19], (const float*)d_in[20],
        (const float*)d_in[21], (const float*)d_in[22], (const float*)d_in[23], (const float*)d_in[24],
        (const float*)d_in[25], (const float*)d_in[26], (const float*)d_in[27], (const float*)d_in[28],
        (float*)d_out);
}

// Round 14
// 214.242 us; speedup vs baseline: 1.7410x; 1.0557x over previous
//
#include <hip/hip_runtime.h>

#define PP    32      // nodes per graph
#define FF    16      // input features
#define HH    4       // heads
#define CC    32      // head dim
#define DD    128     // hidden (H*C)
#define EDIM  5
#define EPG   992     // edges per graph = P*(P-1)
#define NB    512     // graphs

// ---- DPP helpers (HW-validated R4) ------------------------------------------
template <int CTRL>
__device__ __forceinline__ float dpp_add(float v) {
    int t = __builtin_amdgcn_update_dpp(0, __builtin_bit_cast(int, v), CTRL, 0xF, 0xF, true);
    return v + __builtin_bit_cast(float, t);
}
template <int CTRL>
__device__ __forceinline__ float dpp_mov(float v) {
    int t = __builtin_amdgcn_update_dpp(0, __builtin_bit_cast(int, v), CTRL, 0xF, 0xF, true);
    return __builtin_bit_cast(float, t);
}
// full 64-lane sum -> result valid in lane 63
__device__ __forceinline__ float red64(float v) {
    v = dpp_add<0x111>(v);   // row_shr:1
    v = dpp_add<0x112>(v);   // row_shr:2
    v = dpp_add<0x114>(v);   // row_shr:4
    v = dpp_add<0x118>(v);   // row_shr:8
    v = dpp_add<0x142>(v);   // row_bcast:15
    v = dpp_add<0x143>(v);   // row_bcast:31
    return v;
}
// quad butterfly sum -> all 4 lanes hold the sum
__device__ __forceinline__ float redquad(float v) {
    v = dpp_add<0xB1>(v);    // quad_perm [1,0,3,2]  (xor 1)
    v = dpp_add<0x4E>(v);    // quad_perm [2,3,0,1]  (xor 2)
    return v;
}
// quad butterfly max -> all 4 lanes hold the max
__device__ __forceinline__ float maxquad(float v) {
    v = fmaxf(v, dpp_mov<0xB1>(v));
    v = fmaxf(v, dpp_mov<0x4E>(v));
    return v;
}

// ---- GATv2 layer (R8-proven structure) --------------------------------------
// Score phase lane map: s = tid>>4, h = (tid>>2)&3, c4 = tid&3, ch0=(tid&15)*8.
// Edge attrs STAGED INTO LDS (sE == sOut, dead during score phase) in two
// d-halves (16 KB).  Score loop reads via 16-lane broadcast; xr via 2x
// ds_read_b128.  Diagonal d==s staged from a clamped in-bounds edge and
// discarded by softmax.  sS layout: sS[s*128 + d*4 + h].
__device__ __forceinline__ void attention(const float* __restrict__ eattr,
                                          const float* __restrict__ We, const float* __restrict__ att,
                                          const float* __restrict__ bias,
                                          const float* __restrict__ sMsg, const float* __restrict__ sDst,
                                          float* __restrict__ sS, float* __restrict__ sOut,
                                          int tid, long eBase, bool relu)
{
    float* __restrict__ sE = sOut;                    // staging alias (dead until aggregation)
    {
        const int s  = tid >> 4;
        const int ch0 = (tid & 15) * 8;               // h*32 + c4*8
        // preload We[ch0..ch0+7][0..4] (40 consecutive floats), att, xl
        float we[40], at[8], xl[8];
#pragma unroll
        for (int q = 0; q < 10; ++q)
            *(float4*)(we + q * 4) = *(const float4*)(We + ch0 * EDIM + q * 4);
        *(float4*)(at)     = *(const float4*)(att + ch0);
        *(float4*)(at + 4) = *(const float4*)(att + ch0 + 4);
        *(float4*)(xl)     = *(const float4*)(sMsg + s * DD + ch0);
        *(float4*)(xl + 4) = *(const float4*)(sMsg + s * DD + ch0 + 4);

        for (int halfd = 0; halfd < 2; ++halfd) {
            const int d0 = halfd * 16;
            // ---- stage edges (s, d0 + dl): one edge per thread (32s x 16d)
            {
                const int dl = tid & 15;
                const int d = d0 + dl;
                int jj = d - (d > s);
                if (jj > 30) jj = 30;                 // d==s==31 clamp (discarded)
                const float* ea = eattr + (eBase + s * 31 + jj) * EDIM;
                const float e0 = ea[0], e1 = ea[1], e2 = ea[2], e3 = ea[3], e4 = ea[4];
                float* p = sE + (((s << 4) | dl) << 3);
                *(float4*)p = make_float4(e0, e1, e2, e3);
                p[4] = e4;
            }
            __syncthreads();
            // ---- score loop over this d-half: LDS reads only
#pragma unroll 2
            for (int dl = 0; dl < 16; ++dl) {
                const int d = d0 + dl;
                const float* ep = sE + (((s << 4) | dl) << 3);
                const float4 ef = *(const float4*)ep;
                const float e4v = ep[4];
                float xr[8];
                *(float4*)(xr)     = *(const float4*)(sDst + d * DD + ch0);
                *(float4*)(xr + 4) = *(const float4*)(sDst + d * DD + ch0 + 4);
                float acc0 = 0.f, acc1 = 0.f;
#pragma unroll
                for (int c = 0; c < 8; ++c) {
                    float v = xl[c] + xr[c];
                    const float* w = we + c * EDIM;
                    v = fmaf(w[0], ef.x, v); v = fmaf(w[1], ef.y, v); v = fmaf(w[2], ef.z, v);
                    v = fmaf(w[3], ef.w, v); v = fmaf(w[4], e4v, v);
                    v = fmaf(0.4f, fabsf(v), 0.6f * v);   // leaky_relu(., 0.2)
                    if (c & 1) acc1 = fmaf(v, at[c], acc1);
                    else       acc0 = fmaf(v, at[c], acc0);
                }
                const float r = redquad(acc0 + acc1);     // sum over 4 c4-chunks
                if ((tid & 3) == 0)
                    sS[s * DD + d * HH + ((tid >> 2) & 3)] = r;
            }
            __syncthreads();                              // sE half consumed
        }
    }
    // ---- segment softmax over s != d per column (d*4+h): all 512 threads,
    // quad per column, r = tid&3 owns 8 rows, DPP quad reduce.
    {
        const int col = tid >> 2;
        const int r   = tid & 3;
        const int dd  = col >> 2;                     // destination node of this column
        float v[8];
        float mx = -3.4e38f;
#pragma unroll
        for (int i = 0; i < 8; ++i) {
            const int s = r * 8 + i;
            v[i] = sS[s * DD + col];
            mx = (s == dd) ? mx : fmaxf(mx, v[i]);
        }
        mx = maxquad(mx);
        float sum = 0.f;
#pragma unroll
        for (int i = 0; i < 8; ++i) {
            const int s = r * 8 + i;
            float ex = __expf(v[i] - mx);
            ex = (s == dd) ? 0.f : ex;                // diagonal forced to 0
            v[i] = ex; sum += ex;
        }
        sum = redquad(sum);
        const float inv = 1.f / (sum + 1e-16f);
#pragma unroll
        for (int i = 0; i < 8; ++i)
            sS[(r * 8 + i) * DD + col] = v[i] * inv;
    }
    __syncthreads();
    // ---- aggregation: out[d][ch] = bias[ch] + sum_s alpha[s][d,h(ch)] * msg[s][ch]
    {
        const int d = tid >> 4, sub = tid & 15;
#pragma unroll
        for (int half = 0; half < 2; ++half) {
            const int ch4 = half * 16 + sub;
            const int idx = d * HH + (ch4 >> 3);
            const float* bp = bias + ch4 * 4;
            float4 acc = make_float4(bp[0], bp[1], bp[2], bp[3]);
#pragma unroll
            for (int s = 0; s < PP; ++s) {
                const float a = sS[s * DD + idx];     // alpha(d==s) == 0
                const float4 xv = *(const float4*)(sMsg + s * DD + ch4 * 4);
                acc.x = fmaf(a, xv.x, acc.x);
                acc.y = fmaf(a, xv.y, acc.y);
                acc.z = fmaf(a, xv.z, acc.z);
                acc.w = fmaf(a, xv.w, acc.w);
            }
            if (relu) {
                acc.x = fmaxf(acc.x, 0.f); acc.y = fmaxf(acc.y, 0.f);
                acc.z = fmaxf(acc.z, 0.f); acc.w = fmaxf(acc.w, 0.f);
            }
            *(float4*)(sOut + d * DD + ch4 * 4) = acc;
        }
    }
}

extern "C" __global__ void __launch_bounds__(512)
__attribute__((amdgpu_waves_per_eu(4, 4)))
planetwars_gnn_kernel(const float* __restrict__ x, const float* __restrict__ eattr,
                      const float* __restrict__ W1l, const float* __restrict__ b1l,
                      const float* __restrict__ W1r, const float* __restrict__ b1r,
                      const float* __restrict__ W1e, const float* __restrict__ att1, const float* __restrict__ bias1,
                      const float* __restrict__ W2l, const float* __restrict__ b2l,
                      const float* __restrict__ W2r, const float* __restrict__ b2r,
                      const float* __restrict__ W2e, const float* __restrict__ att2, const float* __restrict__ bias2,
                      const float* __restrict__ Wc1, const float* __restrict__ bc1,
                      const float* __restrict__ Wc2, const float* __restrict__ bc2,
                      const float* __restrict__ Ws1, const float* __restrict__ bs1,
                      const float* __restrict__ Ws2, const float* __restrict__ bs2,
                      const float* __restrict__ Wn1, const float* __restrict__ bn1,
                      const float* __restrict__ Wn2, const float* __restrict__ bn2,
                      float* __restrict__ out)
{
    __shared__ __align__(16) float sA[PP * DD];   // xl1 -> xl2
    __shared__ __align__(16) float sB[PP * DD];   // xr1 -> xr2
    __shared__ __align__(16) float sH[PP * DD];   // edge staging | h1 -> h2
    __shared__ __align__(16) float sU[PP * DD];   // x | scores/alpha | g

    const int tid = threadIdx.x;
    const int g = blockIdx.x;
    const long eBase = (long)g * EPG;

    // ---- load x tile (32x16), one element per thread
    sU[tid] = x[g * PP * FF + tid];
    __syncthreads();

    // ---- layer-1 node transforms (K = 16): xl1 -> sA, xr1 -> sB
    {
        const int j = tid & 127, d0 = (tid >> 7) * 8;
        float wl[16], wr[16];
#pragma unroll
        for (int q = 0; q < 4; ++q) {
            *(float4*)(wl + q * 4) = *(const float4*)(W1l + j * FF + q * 4);
            *(float4*)(wr + q * 4) = *(const float4*)(W1r + j * FF + q * 4);
        }
        const float bl = b1l[j], br = b1r[j];
#pragma unroll
        for (int i = 0; i < 8; ++i) {
            const float* xr = sU + (d0 + i) * FF;
            float al = bl, ar = br;
#pragma unroll
            for (int k = 0; k < FF; ++k) {
                const float xv = xr[k];
                al = fmaf(wl[k], xv, al);
                ar = fmaf(wr[k], xv, ar);
            }
            sA[(d0 + i) * DD + j] = al;
            sB[(d0 + i) * DD + j] = ar;
        }
    }
    __syncthreads();

    attention(eattr, W1e, att1, bias1, sA, sB, sU, sH, tid, eBase, false);
    __syncthreads();

    // ---- MeanSubtractionNorm per graph, then ReLU (512 threads, quad/column)
    {
        const int col = tid >> 2, r = tid & 3;
        float v[8];
        float ssum = 0.f;
#pragma unroll
        for (int i = 0; i < 8; ++i) {
            v[i] = sH[(r * 8 + i) * DD + col];
            ssum += v[i];
        }
        ssum = redquad(ssum);
        const float mn = ssum * (1.0f / 32.0f);
#pragma unroll
        for (int i = 0; i < 8; ++i)
            sH[(r * 8 + i) * DD + col] = fmaxf(v[i] - mn, 0.f);
    }
    __syncthreads();

    // ---- fused layer-2 node transforms (K = 128), register-weight scheme.
    // R12 proved the scheme (-13%: L1-scatter was the stall); R12/R13 spilled
    // (acc[16] + pipelined w-chunk loads > 64 regs).  R14: weights stream as
    // SINGLE float4 loads, each consumed by 64 fmaf before the next -> live
    // set ~30 regs, nothing for the allocator to spill; still 32 scattered
    // float4/thread.  Per-output k-order ascending 0..127, same fmaf chain
    // -> bit-identical results.
    // Thread map: j = tid&127, m = (tid>>7)&1 (L/R), half = tid>>8 (wave-
    // uniform); h reads are wave-uniform LDS broadcasts.
    {
        const int j    = tid & 127;
        const int m    = (tid >> 7) & 1;
        const int half = tid >> 8;                    // wave-uniform
        const float* Wrow = (m ? W2r : W2l) + j * DD;
        const float  bini = m ? b2r[j] : b2l[j];
        float acc[16];
#pragma unroll
        for (int i = 0; i < 16; ++i) acc[i] = bini;
        for (int kc = 0; kc < 32; ++kc) {
            const float4 w4 = *(const float4*)(Wrow + kc * 4);
#pragma unroll
            for (int i = 0; i < 16; ++i) {
                const float4 hv = *(const float4*)(sH + (half * 16 + i) * DD + kc * 4);
                acc[i] = fmaf(w4.x, hv.x, acc[i]);
                acc[i] = fmaf(w4.y, hv.y, acc[i]);
                acc[i] = fmaf(w4.z, hv.z, acc[i]);
                acc[i] = fmaf(w4.w, hv.w, acc[i]);
            }
        }
        float* dst = m ? sB : sA;
#pragma unroll
        for (int i = 0; i < 16; ++i)
            dst[(half * 16 + i) * DD + j] = acc[i];
    }
    __syncthreads();

    attention(eattr, W2e, att2, bias2, sA, sB, sU, sH, tid, eBase, true);
    __syncthreads();

    // ---- global mean pool -> sU[0..127] (512 threads, quad per column)
    {
        const int col = tid >> 2, r = tid & 3;
        float ssum = 0.f;
#pragma unroll
        for (int i = 0; i < 8; ++i) ssum += sH[(r * 8 + i) * DD + col];
        ssum = redquad(ssum);
        if (r == 0) sU[col] = ssum * (1.0f / 32.0f);
    }
    __syncthreads();

    // ---- source-actor: fused Ws1-GEMM + Ws2 dot -> logits written directly.
    {
        const int jj = tid & 63, d0 = (tid >> 6) * 4;
        const float b0 = bs1[jj], b1 = bs1[jj + 64];
        float acc0[4], acc1[4];
#pragma unroll
        for (int i = 0; i < 4; ++i) { acc0[i] = b0; acc1[i] = b1; }
        const float* W0 = Ws1 + jj * DD;
        const float* W1 = Ws1 + (jj + 64) * DD;
        for (int k8 = 0; k8 < 16; ++k8) {
            const float4 w00 = *(const float4*)(W0 + k8 * 8), w01 = *(const float4*)(W0 + k8 * 8 + 4);
            const float4 w10 = *(const float4*)(W1 + k8 * 8), w11 = *(const float4*)(W1 + k8 * 8 + 4);
#pragma unroll
            for (int i = 0; i < 4; ++i) {
                const float4 a0 = *(const float4*)(sH + (d0 + i) * DD + k8 * 8);
                const float4 a1 = *(const float4*)(sH + (d0 + i) * DD + k8 * 8 + 4);
                acc0[i] = fmaf(w00.x, a0.x, acc0[i]); acc0[i] = fmaf(w00.y, a0.y, acc0[i]);
                acc0[i] = fmaf(w00.z, a0.z, acc0[i]); acc0[i] = fmaf(w00.w, a0.w, acc0[i]);
                acc0[i] = fmaf(w01.x, a1.x, acc0[i]); acc0[i] = fmaf(w01.y, a1.y, acc0[i]);
                acc0[i] = fmaf(w01.z, a1.z, acc0[i]); acc0[i] = fmaf(w01.w, a1.w, acc0[i]);
                acc1[i] = fmaf(w10.x, a0.x, acc1[i]); acc1[i] = fmaf(w10.y, a0.y, acc1[i]);
                acc1[i] = fmaf(w10.z, a0.z, acc1[i]); acc1[i] = fmaf(w10.w, a0.w, acc1[i]);
                acc1[i] = fmaf(w11.x, a1.x, acc1[i]); acc1[i] = fmaf(w11.y, a1.y, acc1[i]);
                acc1[i] = fmaf(w11.z, a1.z, acc1[i]); acc1[i] = fmaf(w11.w, a1.w, acc1[i]);
            }
        }
        const float ws2a = Ws2[jj], ws2b = Ws2[jj + 64];
        const float bias2s = bs2[0];
#pragma unroll
        for (int i = 0; i < 4; ++i) {
            const float t = fmaf(fmaxf(acc0[i], 0.f), ws2a, fmaxf(acc1[i], 0.f) * ws2b);
            const float r = red64(t);                 // lane 63 holds node logit
            if ((tid & 63) == 63) out[g * 34 + 2 + d0 + i] = r + bias2s;
        }
    }

    // ---- value / noop: wave 0 = critic, wave 1 = noop (fused hidden + dot)
    if (tid < 128) {
        const int w = tid >> 6, j = tid & 63;
        const float* Wa = (w ? Wn1 : Wc1);
        const float* ba = (w ? bn1 : bc1);
        const float* Wb = (w ? Wn2 : Wc2);
        const float  bb = (w ? bn2 : bc2)[0];
        float h0 = ba[j], h1 = ba[j + 64];
        const float* R0 = Wa + j * DD;
        const float* R1 = Wa + (j + 64) * DD;
#pragma unroll
        for (int k8 = 0; k8 < 16; ++k8) {
            const float4 g0 = *(const float4*)(sU + k8 * 8);
            const float4 g1 = *(const float4*)(sU + k8 * 8 + 4);
            const float4 p00 = *(const float4*)(R0 + k8 * 8), p01 = *(const float4*)(R0 + k8 * 8 + 4);
            const float4 p10 = *(const float4*)(R1 + k8 * 8), p11 = *(const float4*)(R1 + k8 * 8 + 4);
            h0 = fmaf(p00.x, g0.x, h0); h0 = fmaf(p00.y, g0.y, h0);
            h0 = fmaf(p00.z, g0.z, h0); h0 = fmaf(p00.w, g0.w, h0);
            h0 = fmaf(p01.x, g1.x, h0); h0 = fmaf(p01.y, g1.y, h0);
            h0 = fmaf(p01.z, g1.z, h0); h0 = fmaf(p01.w, g1.w, h0);
            h1 = fmaf(p10.x, g0.x, h1); h1 = fmaf(p10.y, g0.y, h1);
            h1 = fmaf(p10.z, g0.z, h1); h1 = fmaf(p10.w, g0.w, h1);
            h1 = fmaf(p11.x, g1.x, h1); h1 = fmaf(p11.y, g1.y, h1);
            h1 = fmaf(p11.z, g1.z, h1); h1 = fmaf(p11.w, g1.w, h1);
        }
        const float t = fmaf(fmaxf(h0, 0.f), Wb[j], fmaxf(h1, 0.f) * Wb[j + 64]);
        const float r = red64(t);
        if (j == 63) out[g * 34 + w] = r + bb;
    }
}

extern "C" void kernel_launch(void* const* d_in, const int* in_sizes, int n_in,
                              void* d_out, int out_size, void* d_ws, size_t ws_size,
                              hipStream_t stream)
{
    (void)in_sizes; (void)n_in; (void)d_ws; (void)ws_size; (void)out_size;
    // d_in[1] (edge_index) unused: edge structure is analytic (validated R3).
    planetwars_gnn_kernel<<<dim3(NB), dim3(512), 0, stream>>>(
        (const float*)d_in[0], (const float*)d_in[2],
        (const float*)d_in[3], (const float*)d_in[4], (const float*)d_in[5], (const float*)d_in[6],
        (const float*)d_in[7], (const float*)d_in[8], (const float*)d_in[9],
        (const float*)d_in[10], (const float*)d_in[11], (const float*)d_in[12], (const float*)d_in[13],
        (const float*)d_in[14], (const float*)d_in[15], (const float*)d_in[16],
        (const float*)d_in[17], (const float*)d_in[18], (const float*)d_in[19], (const float*)d_in[20],
        (const float*)d_in[21], (const float*)d_in[22], (const float*)d_in[23], (const float*)d_in[24],
        (const float*)d_in[25], (const float*)d_in[26], (const float*)d_in[27], (const float*)d_in[28],
        (float*)d_out);
}